// Round 4
// baseline (535.133 us; speedup 1.0000x reference)
//
#include <hip/hip_runtime.h>
#include <hip/hip_bf16.h>
#include <math.h>
#include <stddef.h>

#define DEV __device__ __forceinline__
__device__ const float BNS = 0.99999500003749968f; // 1/sqrt(1+1e-5)

typedef __bf16 bf16x8 __attribute__((ext_vector_type(8)));
typedef float  f32x4  __attribute__((ext_vector_type(4)));

DEV unsigned short f2bs(float v){
  union{ __hip_bfloat16 b; unsigned short u; } c; c.b=__float2bfloat16(v); return c.u;
}
DEV float bs2f(unsigned short u){
  union{ unsigned short u; __hip_bfloat16 b; } c; c.u=u; return __bfloat162float(c.b);
}

// Geometry: B=2, M=256 -> 512 bm groups, N=64 pts, KNN=16, CIN=64,
// edge1 O=64, edge2 O=128, SUMM=192, CALIB=64, EXP=256/512, OUT=256. f32 I/O.
//
// Activation layout for MFMA stages: bf16 split, [bm*64+n][2][K] (hi row, lo row).
// Weights for MFMA stages: bf16 split, original [O][K] layout (k-contiguous).

// ---------------- kernel A: knn + build x0 (64ch x 64pts, f32) --------------
__global__ __launch_bounds__(64) void k_knn(const float* __restrict__ xyz,
    const float* __restrict__ feats, int* __restrict__ idxo, float* __restrict__ x0){
  int bm = blockIdx.x; int n = threadIdx.x;
  __shared__ float sx0[64], sx1[64], sx2[64], sxx[64];
  __shared__ float pd[64][65];
  const float* xp = xyz + (size_t)(bm*64+n)*3;
  float px=xp[0], py=xp[1], pz=xp[2];
  sx0[n]=px; sx1[n]=py; sx2[n]=pz; sxx[n]=px*px+py*py+pz*pz;
  __syncthreads();
  float xxn = sxx[n];
  for(int m=0;m<64;m++){
    float inner = px*sx0[m]+py*sx1[m]+pz*sx2[m];
    pd[n][m] = 2.0f*inner - xxn - sxx[m];
  }
  int* ip = idxo + bm*1024 + n*16;
  for(int j=0;j<16;j++){
    float best=-3.4e38f; int bi=0;
    for(int m=0;m<64;m++){ float v=pd[n][m]; if(v>best){best=v;bi=m;} }
    ip[j]=bi; pd[n][bi]=-3.4e38f;  // strict > keeps lowest index on ties (lax.top_k)
  }
  float* xb = x0 + (size_t)bm*4096;
  xb[0*64+n]=px; xb[1*64+n]=py; xb[2*64+n]=pz;
  const float* fp = feats + (size_t)(bm*64+n)*61;
  for(int c=0;c<61;c++) xb[(3+c)*64+n]=fp[c];
}

// ---------------- edgeconv (f32 VALU; W loads wave-uniform -> s_load) -------
// Writes cat split layout [n][2][192] at column offset coloff; edge1 also
// writes f32 [o][64] buffer (a1f) for edge2's staging.
template<int O>
__global__ __launch_bounds__(256) void k_edge(const float* __restrict__ xin_g, int ld_in,
   const int* __restrict__ idxg, const float* __restrict__ W, const float* __restrict__ gg,
   const float* __restrict__ bb, unsigned short* __restrict__ cat, int coloff,
   float* __restrict__ a1f){
  __shared__ float xin[4096];
  __shared__ float zs[4096];
  __shared__ float dds[4096];
  int bm=blockIdx.x, tid=threadIdx.x;
  for(int i=tid;i<4096;i+=256) xin[i]=xin_g[(size_t)bm*ld_in+i];
  const int* ip0 = idxg + bm*1024;
  for(int oc=0; oc<O; oc+=64){
    __syncthreads();
    for(int i=tid;i<4096;i+=256){
      int o=oc+(i>>6), m=i&63;   // i>>6 wave-uniform -> W reads go scalar path
      float az=0.f, ad=0.f;
      #pragma unroll 8
      for(int c=0;c<64;c++){
        float w1v=W[o*128+c];
        float w2v=W[o*128+64+c];
        float xv=xin[c*64+m];
        az += w1v*xv; ad += (w2v-w1v)*xv;
      }
      zs[i]=az; dds[i]=ad;
    }
    __syncthreads();
    for(int i=tid;i<4096;i+=256){
      int o=oc+(i>>6), n=i&63;
      float s=gg[o]*BNS, bi=bb[o];
      float base=dds[i];
      const int* ip=ip0+n*16;
      int zrow=(i>>6)<<6;
      float v=0.f;  // relu(max) == max(0, max_k pre-relu)
      #pragma unroll
      for(int k=0;k<16;k++){ int mi=ip[k]; v=fmaxf(v, s*(zs[zrow+mi]+base)+bi); }
      if(a1f) a1f[(size_t)bm*4096 + o*64 + n] = v;
      size_t cb = ((size_t)bm*64+n)*384 + coloff + o;  // [n][2][192]
      unsigned short hv=f2bs(v);
      cat[cb]     = hv;
      cat[cb+192] = f2bs(v - bs2f(hv));
    }
  }
}

// ---------------- split f32 -> bf16 hi/lo -----------------------------------
__global__ __launch_bounds__(256) void k_split(const float* __restrict__ in,
    unsigned short* __restrict__ hi, unsigned short* __restrict__ lo, int n){
  int i = blockIdx.x*256 + threadIdx.x;
  if(i<n){ float v=in[i]; unsigned short h=f2bs(v); hi[i]=h; lo[i]=f2bs(v-bs2f(h)); }
}

// ---------------- MFMA GEMM, split-bf16 (3 mfma), LDS-free -----------------
// Wave computes 32 rows (o) x 64 cols (n) of one bm group via 16x16x32 bf16.
// grid = (512, ceil(O/128)), block = 256 (4 waves).
// EPI 0: write bf16 split out [n][2][O]: relu(acc*s+b)
// EPI 1: gate: Og(cat ushort [n][2][192]) *= sigmoid(acc + sg[o])
// EPI 2: pool f32: pool[(b*512+o)*256+m] = max(0, max_n(acc*s+b))
template<int K, int EPI>
__global__ __launch_bounds__(256) void k_mm(
    const unsigned short* __restrict__ Whi, const unsigned short* __restrict__ Wlo,
    const unsigned short* __restrict__ X, void* __restrict__ Og,
    const float* __restrict__ sg, const float* __restrict__ bg, int O){
  int bm = blockIdx.x;
  int wid = threadIdx.x >> 6, lane = threadIdx.x & 63;
  int o_w = blockIdx.y*128 + wid*32;
  if(o_w >= O) return;
  int l15 = lane & 15, q = lane >> 4;
  f32x4 acc[2][4];
  #pragma unroll
  for(int a=0;a<2;a++)
    #pragma unroll
    for(int d=0;d<4;d++) acc[a][d] = (f32x4){0.f,0.f,0.f,0.f};
  size_t ab0 = (size_t)(o_w +      l15)*K + q*8;
  size_t ab1 = (size_t)(o_w + 16 + l15)*K + q*8;
  size_t xb  = ((size_t)bm*64 + l15)*2*K + q*8;
  #pragma unroll
  for(int kc=0; kc<K/32; kc++){
    int k0 = kc*32;
    bf16x8 a0h = *(const bf16x8*)(Whi + ab0 + k0);
    bf16x8 a0l = *(const bf16x8*)(Wlo + ab0 + k0);
    bf16x8 a1h = *(const bf16x8*)(Whi + ab1 + k0);
    bf16x8 a1l = *(const bf16x8*)(Wlo + ab1 + k0);
    #pragma unroll
    for(int nt=0; nt<4; nt++){
      const unsigned short* xp = X + xb + (size_t)nt*16*2*K + k0;
      bf16x8 bh = *(const bf16x8*)xp;
      bf16x8 bl = *(const bf16x8*)(xp + K);
      acc[0][nt] = __builtin_amdgcn_mfma_f32_16x16x32_bf16(a0h, bh, acc[0][nt], 0,0,0);
      acc[0][nt] = __builtin_amdgcn_mfma_f32_16x16x32_bf16(a0h, bl, acc[0][nt], 0,0,0);
      acc[0][nt] = __builtin_amdgcn_mfma_f32_16x16x32_bf16(a0l, bh, acc[0][nt], 0,0,0);
      acc[1][nt] = __builtin_amdgcn_mfma_f32_16x16x32_bf16(a1h, bh, acc[1][nt], 0,0,0);
      acc[1][nt] = __builtin_amdgcn_mfma_f32_16x16x32_bf16(a1h, bl, acc[1][nt], 0,0,0);
      acc[1][nt] = __builtin_amdgcn_mfma_f32_16x16x32_bf16(a1l, bh, acc[1][nt], 0,0,0);
    }
  }
  // C/D: col(n within tile)=lane&15, row(o within tile)=q*4+reg  [m89]
  if(EPI==0){
    unsigned short* ob = (unsigned short*)Og;
    #pragma unroll
    for(int mt=0; mt<2; mt++){
      int ob0 = o_w + mt*16 + q*4;
      float s0[4], b0[4];
      #pragma unroll
      for(int r=0;r<4;r++){ s0[r]=sg[ob0+r]*BNS; b0[r]=bg[ob0+r]; }
      #pragma unroll
      for(int nt=0; nt<4; nt++){
        int n = nt*16 + l15;
        size_t row = ((size_t)bm*64+n)*2*O;
        unsigned short hv[4], lv[4];
        #pragma unroll
        for(int r=0;r<4;r++){
          float v = fmaxf(acc[mt][nt][r]*s0[r]+b0[r], 0.f);
          hv[r]=f2bs(v); lv[r]=f2bs(v - bs2f(hv[r]));
        }
        *(ushort4*)(ob + row + ob0)     = make_ushort4(hv[0],hv[1],hv[2],hv[3]);
        *(ushort4*)(ob + row + O + ob0) = make_ushort4(lv[0],lv[1],lv[2],lv[3]);
      }
    }
  } else if(EPI==1){
    unsigned short* cat = (unsigned short*)Og;   // [n][2][192]
    #pragma unroll
    for(int mt=0; mt<2; mt++){
      int ob0 = o_w + mt*16 + q*4;
      float bi[4];
      #pragma unroll
      for(int r=0;r<4;r++) bi[r]=sg[ob0+r];
      #pragma unroll
      for(int nt=0; nt<4; nt++){
        int n = nt*16 + l15;
        size_t row = ((size_t)bm*64+n)*384;
        ushort4 hv = *(ushort4*)(cat + row + ob0);
        ushort4 lv = *(ushort4*)(cat + row + 192 + ob0);
        unsigned short h[4]={hv.x,hv.y,hv.z,hv.w}, l[4]={lv.x,lv.y,lv.z,lv.w};
        #pragma unroll
        for(int r=0;r<4;r++){
          float g = 1.f/(1.f+__expf(-(acc[mt][nt][r]+bi[r])));
          float f = (bs2f(h[r])+bs2f(l[r]))*g;
          h[r]=f2bs(f); l[r]=f2bs(f-bs2f(h[r]));
        }
        *(ushort4*)(cat + row + ob0)       = make_ushort4(h[0],h[1],h[2],h[3]);
        *(ushort4*)(cat + row + 192 + ob0) = make_ushort4(l[0],l[1],l[2],l[3]);
      }
    }
  } else {
    float* pool = (float*)Og;
    int b = bm>>8, m = bm&255;
    #pragma unroll
    for(int mt=0; mt<2; mt++){
      int ob0 = o_w + mt*16 + q*4;
      #pragma unroll
      for(int r=0;r<4;r++){
        float s=sg[ob0+r]*BNS, bi=bg[ob0+r];
        float v = acc[mt][0][r]*s+bi;
        v = fmaxf(v, acc[mt][1][r]*s+bi);
        v = fmaxf(v, acc[mt][2][r]*s+bi);
        v = fmaxf(v, acc[mt][3][r]*s+bi);
        v = fmaxf(v, 0.f);
        v = fmaxf(v, __shfl_xor(v,1));
        v = fmaxf(v, __shfl_xor(v,2));
        v = fmaxf(v, __shfl_xor(v,4));
        v = fmaxf(v, __shfl_xor(v,8));
        if(l15==0) pool[((size_t)b*512 + ob0+r)*256 + m] = v;
      }
    }
  }
}

// ---------------- red: 512->256 bn relu, then bn(x+x,g1,b1) -----------------
__global__ __launch_bounds__(256) void k_red(const float* __restrict__ pool,
   const float* __restrict__ W, const float* __restrict__ g, const float* __restrict__ b,
   const float* __restrict__ g1, const float* __restrict__ b1, float* __restrict__ x1){
  int e=blockIdx.x*256+threadIdx.x;
  int bb=e>>16, o=(e>>8)&255, m=e&255;
  const float* pp=pool+(size_t)bb*131072+m;
  const float* wr=W+o*512;
  float acc=0.f;
  #pragma unroll 4
  for(int c=0;c<512;c++) acc+=wr[c]*pp[(size_t)c*256];
  float r=fmaxf(acc*g[o]*BNS+b[o],0.f);
  x1[e]=2.f*r*(g1[o]*BNS)+b1[o];
}

// ---------------- sc1: h = relu(W@x1 + b) -----------------------------------
__global__ __launch_bounds__(256) void k_sc1(const float* __restrict__ x1,
   const float* __restrict__ W, const float* __restrict__ b, float* __restrict__ h){
  int e=blockIdx.x*256+threadIdx.x;
  int bb=e>>16, o=(e>>8)&255, m=e&255;
  const float* xp=x1+(size_t)bb*65536+m;
  const float* wr=W+o*256;
  float acc=0.f;
  #pragma unroll 4
  for(int c=0;c<256;c++) acc+=wr[c]*xp[(size_t)c*256];
  h[e]=fmaxf(acc+b[o],0.f);
}

// ---------------- sc2 + residual + bn2 -> f32 out ---------------------------
__global__ __launch_bounds__(256) void k_sc2(const float* __restrict__ h,
   const float* __restrict__ x1, const float* __restrict__ W, const float* __restrict__ b,
   const float* __restrict__ g2, const float* __restrict__ b2, float* __restrict__ out){
  int e=blockIdx.x*256+threadIdx.x;
  int bb=e>>16, o=(e>>8)&255, m=e&255;
  const float* hp=h+(size_t)bb*65536+m;
  const float* wr=W+o*256;
  float acc=0.f;
  #pragma unroll 4
  for(int c=0;c<256;c++) acc+=wr[c]*hp[(size_t)c*256];
  float v=x1[e]+acc+b[o];
  out[e]=v*(g2[o]*BNS)+b2[o];
}

extern "C" void kernel_launch(void* const* d_in, const int* in_sizes, int n_in,
                              void* d_out, int out_size, void* d_ws, size_t ws_size,
                              hipStream_t stream){
  const float* xyz     =(const float*)d_in[0];
  const float* feats   =(const float*)d_in[1];
  const float* e1_w    =(const float*)d_in[2];
  const float* e1_g    =(const float*)d_in[3];
  const float* e1_b    =(const float*)d_in[4];
  const float* e2_w    =(const float*)d_in[5];
  const float* e2_g    =(const float*)d_in[6];
  const float* e2_b    =(const float*)d_in[7];
  const float* cal1_w  =(const float*)d_in[8];
  const float* cal1_g  =(const float*)d_in[9];
  const float* cal1_b  =(const float*)d_in[10];
  const float* cal2_w  =(const float*)d_in[11];
  const float* cal2_bias=(const float*)d_in[12];
  const float* exp1_w  =(const float*)d_in[13];
  const float* exp1_g  =(const float*)d_in[14];
  const float* exp1_b  =(const float*)d_in[15];
  const float* exp2_w  =(const float*)d_in[16];
  const float* exp2_g  =(const float*)d_in[17];
  const float* exp2_b  =(const float*)d_in[18];
  const float* red_w   =(const float*)d_in[19];
  const float* red_g   =(const float*)d_in[20];
  const float* red_b   =(const float*)d_in[21];
  const float* sc1_w   =(const float*)d_in[22];
  const float* sc1_b   =(const float*)d_in[23];
  const float* sc2_w   =(const float*)d_in[24];
  const float* sc2_b   =(const float*)d_in[25];
  const float* sc_n1_g =(const float*)d_in[26];
  const float* sc_n1_b =(const float*)d_in[27];
  const float* sc_n2_g =(const float*)d_in[28];
  const float* sc_n2_b =(const float*)d_in[29];

  char* wsb=(char*)d_ws;
  // workspace (peak 71,303,168 B == round-3 proven usage):
  // [0,2M):    idx (knn..edge2)          -> then W splits (Whi@0, Wlo@1M)
  // [2M,10M):  x0 f32 (knn..edge1)       -> then c1 split [n][2][64] (8MB)
  // [10M,12M): a1f head / later pool(1M)+x1(.5M)+h(.5M)
  // [10M,18M): a1f f32 (edge1..edge2)  (pool/x1/h written only after edge2)
  // [12M,44M): p1 split [n][2][256] (32MB, exp1..exp2)
  // [44M,68M): cat split [n][2][192] (24MB, edge1..exp1)
  int*            idx =(int*)           (wsb);
  unsigned short* Whi =(unsigned short*)(wsb);
  unsigned short* Wlo =(unsigned short*)(wsb + (1u<<20));
  float*          x0  =(float*)         (wsb + (2u<<20));
  unsigned short* c1s =(unsigned short*)(wsb + (2u<<20));
  float*          a1f =(float*)         (wsb + (10u<<20));
  float*          pool=(float*)         (wsb + (10u<<20));
  float*          x1  =(float*)         (wsb + (11u<<20));
  float*          hbuf=(float*)         (wsb + (11u<<20) + 524288);
  unsigned short* p1s =(unsigned short*)(wsb + (12u<<20));
  unsigned short* cats=(unsigned short*)(wsb + (12u<<20) + 33554432);
  // W split sub-offsets (elements):
  unsigned short* c1w_h=Whi;           unsigned short* c1w_l=Wlo;            // 64x192
  unsigned short* c2w_h=Whi+12288;     unsigned short* c2w_l=Wlo+12288;      // 192x64
  unsigned short* e1w_h=Whi+24576;     unsigned short* e1w_l=Wlo+24576;      // 256x192
  unsigned short* e2w_h=Whi+73728;     unsigned short* e2w_l=Wlo+73728;      // 512x256

  k_knn      <<<512, 64,0,stream>>>(xyz,feats,idx,x0);
  k_edge< 64><<<512,256,0,stream>>>(x0,  4096,idx,e1_w,e1_g,e1_b,cats, 0,a1f);
  k_edge<128><<<512,256,0,stream>>>(a1f, 4096,idx,e2_w,e2_g,e2_b,cats,64,nullptr);
  // split weights (idx region now dead)
  k_split    <<< 48,256,0,stream>>>(cal1_w,c1w_h,c1w_l, 12288);
  k_split    <<< 48,256,0,stream>>>(cal2_w,c2w_h,c2w_l, 12288);
  k_split    <<<192,256,0,stream>>>(exp1_w,e1w_h,e1w_l, 49152);
  k_split    <<<512,256,0,stream>>>(exp2_w,e2w_h,e2w_l,131072);
  // cal1: 192->64 bn+relu -> c1 split
  k_mm<192,0><<<dim3(512,1),256,0,stream>>>(c1w_h,c1w_l,cats,(void*)c1s,cal1_g,cal1_b, 64);
  // cal2: 64->192 +bias, sigmoid gate cat in place
  k_mm< 64,1><<<dim3(512,2),256,0,stream>>>(c2w_h,c2w_l,c1s,(void*)cats,cal2_bias,cal2_bias,192);
  // exp1: 192->256 bn+relu -> p1 split
  k_mm<192,0><<<dim3(512,2),256,0,stream>>>(e1w_h,e1w_l,cats,(void*)p1s,exp1_g,exp1_b,256);
  // exp2: 256->512 bn+relu + maxpool over n -> pool f32
  k_mm<256,2><<<dim3(512,4),256,0,stream>>>(e2w_h,e2w_l,p1s,(void*)pool,exp2_g,exp2_b,512);
  k_red      <<<512,256,0,stream>>>(pool,red_w,red_g,red_b,sc_n1_g,sc_n1_b,x1);
  k_sc1      <<<512,256,0,stream>>>(x1,sc1_w,sc1_b,hbuf);
  k_sc2      <<<512,256,0,stream>>>(hbuf,x1,sc2_w,sc2_b,sc_n2_g,sc_n2_b,(float*)d_out);
}

// Round 5
// 410.793 us; speedup vs baseline: 1.3027x; 1.3027x over previous
//
#include <hip/hip_runtime.h>
#include <hip/hip_bf16.h>
#include <math.h>
#include <stddef.h>

#define DEV __device__ __forceinline__
__device__ const float BNS = 0.99999500003749968f; // 1/sqrt(1+1e-5)

typedef __bf16 bf16x8 __attribute__((ext_vector_type(8)));
typedef float  f32x4  __attribute__((ext_vector_type(4)));

DEV unsigned short f2bs(float v){
  union{ __hip_bfloat16 b; unsigned short u; } c; c.b=__float2bfloat16(v); return c.u;
}
DEV float bs2f(unsigned short u){
  union{ unsigned short u; __hip_bfloat16 b; } c; c.u=u; return __bfloat162float(c.b);
}

// Geometry: B=2, M=256 -> 512 bm groups, N=64 pts, KNN=16, CIN=64,
// edge1 O=64, edge2 O=128, SUMM=192, CALIB=64, EXP=256/512, OUT=256. f32 I/O.
// Split-bf16 activation layout: [row][2][K] ushort (hi row, lo row), row=bm*64+n.

// ---------------- kernel A: knn + x0 split [n][2][64] -----------------------
__global__ __launch_bounds__(64) void k_knn(const float* __restrict__ xyz,
    const float* __restrict__ feats, int* __restrict__ idxo,
    unsigned short* __restrict__ x0s){
  int bm = blockIdx.x; int n = threadIdx.x;
  __shared__ float sx0[64], sx1[64], sx2[64], sxx[64];
  __shared__ float pd[64][65];
  __shared__ unsigned short sb[64*130];   // split staging, row stride 130
  const float* xp = xyz + (size_t)(bm*64+n)*3;
  float px=xp[0], py=xp[1], pz=xp[2];
  sx0[n]=px; sx1[n]=py; sx2[n]=pz; sxx[n]=px*px+py*py+pz*pz;
  __syncthreads();
  float xxn = sxx[n];
  for(int m=0;m<64;m++){
    float inner = px*sx0[m]+py*sx1[m]+pz*sx2[m];
    pd[n][m] = 2.0f*inner - xxn - sxx[m];
  }
  int* ip = idxo + bm*1024 + n*16;
  for(int j=0;j<16;j++){
    float best=-3.4e38f; int bi=0;
    for(int m=0;m<64;m++){ float v=pd[n][m]; if(v>best){best=v;bi=m;} }
    ip[j]=bi; pd[n][bi]=-3.4e38f;  // strict > keeps lowest index on ties (lax.top_k)
  }
  // split row n into sb
  unsigned short* r = sb + n*130;
  {
    unsigned short h;
    h=f2bs(px); r[0]=h; r[64]=f2bs(px-bs2f(h));
    h=f2bs(py); r[1]=h; r[65]=f2bs(py-bs2f(h));
    h=f2bs(pz); r[2]=h; r[66]=f2bs(pz-bs2f(h));
  }
  const float* fp = feats + (size_t)(bm*64+n)*61;
  for(int c=0;c<61;c++){
    float v=fp[c]; unsigned short h=f2bs(v);
    r[3+c]=h; r[64+3+c]=f2bs(v-bs2f(h));
  }
  __syncthreads();
  // coalesced write: 64 rows x 128 ushort = 4096 uint
  unsigned int* g32 = (unsigned int*)(x0s + (size_t)bm*8192);
  const unsigned int* s32 = (const unsigned int*)sb;
  for(int i=0;i<64;i++) g32[i*64 + n] = s32[i*65 + n];
}

// ---------------- split f32 -> bf16 hi/lo (cal/exp weights) -----------------
__global__ __launch_bounds__(256) void k_split(const float* __restrict__ in,
    unsigned short* __restrict__ hi, unsigned short* __restrict__ lo, int n){
  int i = blockIdx.x*256 + threadIdx.x;
  if(i<n){ float v=in[i]; unsigned short h=f2bs(v); hi[i]=h; lo[i]=f2bs(v-bs2f(h)); }
}

// ---------------- edge weight prep: rows [W1 ; W2-W1], split bf16 -----------
__global__ __launch_bounds__(256) void k_splite(const float* __restrict__ W,
    unsigned short* __restrict__ hi, unsigned short* __restrict__ lo, int O){
  int i = blockIdx.x*256 + threadIdx.x;   // over 2*O*64
  int row = i>>6, c = i&63;
  float v = (row<O) ? W[row*128+c] : (W[(row-O)*128+64+c] - W[(row-O)*128+c]);
  unsigned short h=f2bs(v); hi[i]=h; lo[i]=f2bs(v-bs2f(h));
}

// ---------------- edgeconv via MFMA + LDS gather ---------------------------
// Wc (split, [2O][64]): rows [0,O)=W1, [O,2O)=W2-W1.
// X split rows (bm*64+n)*RS, lo at +LO. out -> cat [n][2][192] at coloff.
// v(o,n) = max(0, s[o]*( max_k z[o,idx[n][k]] + dd[o,n] ) + b[o]),  s>0.
template<int O>
__global__ __launch_bounds__(256) void k_edge2(
    const unsigned short* __restrict__ Wh, const unsigned short* __restrict__ Wl,
    const unsigned short* __restrict__ X, int RS, int LO,
    const int* __restrict__ idxg, const float* __restrict__ gg,
    const float* __restrict__ bb, unsigned short* __restrict__ cat, int coloff){
  __shared__ float zs[64*65];
  __shared__ float ds[64*65];
  int bm = blockIdx.x;
  int tid = threadIdx.x, wid = tid>>6, lane = tid&63;
  int l15 = lane&15, q = lane>>4;
  const int* ip0 = idxg + bm*1024;
  size_t xrow = ((size_t)bm*64 + l15)*RS;
  for(int ch=0; ch<O/64; ch++){
    // MFMA: z rows (wid<2) / dd rows (wid>=2), 32 rows per wave
    int rbase = ((wid<2)?0:O) + ch*64 + (wid&1)*32;
    f32x4 acc[2][4];
    #pragma unroll
    for(int a=0;a<2;a++)
      #pragma unroll
      for(int d=0;d<4;d++) acc[a][d]=(f32x4){0.f,0.f,0.f,0.f};
    #pragma unroll
    for(int kc=0;kc<2;kc++){
      int k0=kc*32;
      size_t a0=(size_t)(rbase+l15)*64 + k0 + q*8;
      size_t a1=(size_t)(rbase+16+l15)*64 + k0 + q*8;
      bf16x8 a0h=*(const bf16x8*)(Wh+a0), a0l=*(const bf16x8*)(Wl+a0);
      bf16x8 a1h=*(const bf16x8*)(Wh+a1), a1l=*(const bf16x8*)(Wl+a1);
      #pragma unroll
      for(int nt=0;nt<4;nt++){
        const unsigned short* xp = X + xrow + (size_t)nt*16*RS + k0 + q*8;
        bf16x8 bh=*(const bf16x8*)xp, bl=*(const bf16x8*)(xp+LO);
        acc[0][nt]=__builtin_amdgcn_mfma_f32_16x16x32_bf16(a0h,bh,acc[0][nt],0,0,0);
        acc[0][nt]=__builtin_amdgcn_mfma_f32_16x16x32_bf16(a0h,bl,acc[0][nt],0,0,0);
        acc[0][nt]=__builtin_amdgcn_mfma_f32_16x16x32_bf16(a0l,bh,acc[0][nt],0,0,0);
        acc[1][nt]=__builtin_amdgcn_mfma_f32_16x16x32_bf16(a1h,bh,acc[1][nt],0,0,0);
        acc[1][nt]=__builtin_amdgcn_mfma_f32_16x16x32_bf16(a1h,bl,acc[1][nt],0,0,0);
        acc[1][nt]=__builtin_amdgcn_mfma_f32_16x16x32_bf16(a1l,bh,acc[1][nt],0,0,0);
      }
    }
    __syncthreads();   // prev chunk's gather done before overwrite
    float* dst = (wid<2)? zs : ds;
    int ro = (wid&1)*32;
    #pragma unroll
    for(int mt=0;mt<2;mt++)
      #pragma unroll
      for(int nt=0;nt<4;nt++)
        #pragma unroll
        for(int rr=0;rr<4;rr++)
          dst[(ro+mt*16+q*4+rr)*65 + nt*16+l15] = acc[mt][nt][rr];
    __syncthreads();
    // gather: lane = o (within chunk), wave wid covers n = wid*16+j
    int o = ch*64 + lane;
    float s = gg[o]*BNS, bi = bb[o];
    #pragma unroll 4
    for(int j=0;j<16;j++){
      int n = wid*16 + j;
      const int* ip = ip0 + n*16;
      float mz = -3.4e38f;
      #pragma unroll
      for(int k=0;k<16;k++) mz = fmaxf(mz, zs[lane*65 + ip[k]]);
      float v = fmaxf(s*(mz + ds[lane*65 + n]) + bi, 0.f);
      unsigned short hv = f2bs(v);
      size_t cb = ((size_t)bm*64+n)*384 + coloff + o;
      cat[cb] = hv; cat[cb+192] = f2bs(v - bs2f(hv));
    }
    __syncthreads();
  }
}

// ---------------- MFMA GEMM, split-bf16 (3 mfma), LDS-free -----------------
// EPI 0: write split out [n][2][O]: relu(acc*s+b)
// EPI 1: gate cat [n][2][192] *= sigmoid(acc + sg[o])
// EPI 2: pool f32: pool[(b*512+o)*256+m] = max(0, max_n(acc*s+b))
template<int K, int EPI>
__global__ __launch_bounds__(256) void k_mm(
    const unsigned short* __restrict__ Whi, const unsigned short* __restrict__ Wlo,
    const unsigned short* __restrict__ X, void* __restrict__ Og,
    const float* __restrict__ sg, const float* __restrict__ bg, int O){
  int bm = blockIdx.x;
  int wid = threadIdx.x >> 6, lane = threadIdx.x & 63;
  int o_w = blockIdx.y*128 + wid*32;
  if(o_w >= O) return;
  int l15 = lane & 15, q = lane >> 4;
  f32x4 acc[2][4];
  #pragma unroll
  for(int a=0;a<2;a++)
    #pragma unroll
    for(int d=0;d<4;d++) acc[a][d] = (f32x4){0.f,0.f,0.f,0.f};
  size_t ab0 = (size_t)(o_w +      l15)*K + q*8;
  size_t ab1 = (size_t)(o_w + 16 + l15)*K + q*8;
  size_t xb  = ((size_t)bm*64 + l15)*2*K + q*8;
  #pragma unroll
  for(int kc=0; kc<K/32; kc++){
    int k0 = kc*32;
    bf16x8 a0h = *(const bf16x8*)(Whi + ab0 + k0);
    bf16x8 a0l = *(const bf16x8*)(Wlo + ab0 + k0);
    bf16x8 a1h = *(const bf16x8*)(Whi + ab1 + k0);
    bf16x8 a1l = *(const bf16x8*)(Wlo + ab1 + k0);
    #pragma unroll
    for(int nt=0; nt<4; nt++){
      const unsigned short* xp = X + xb + (size_t)nt*16*2*K + k0;
      bf16x8 bh = *(const bf16x8*)xp;
      bf16x8 bl = *(const bf16x8*)(xp + K);
      acc[0][nt] = __builtin_amdgcn_mfma_f32_16x16x32_bf16(a0h, bh, acc[0][nt], 0,0,0);
      acc[0][nt] = __builtin_amdgcn_mfma_f32_16x16x32_bf16(a0h, bl, acc[0][nt], 0,0,0);
      acc[0][nt] = __builtin_amdgcn_mfma_f32_16x16x32_bf16(a0l, bh, acc[0][nt], 0,0,0);
      acc[1][nt] = __builtin_amdgcn_mfma_f32_16x16x32_bf16(a1h, bh, acc[1][nt], 0,0,0);
      acc[1][nt] = __builtin_amdgcn_mfma_f32_16x16x32_bf16(a1h, bl, acc[1][nt], 0,0,0);
      acc[1][nt] = __builtin_amdgcn_mfma_f32_16x16x32_bf16(a1l, bh, acc[1][nt], 0,0,0);
    }
  }
  // C/D: col(n)=lane&15, row(o)=q*4+reg  [m89]
  if(EPI==0){
    unsigned short* ob = (unsigned short*)Og;
    #pragma unroll
    for(int mt=0; mt<2; mt++){
      int ob0 = o_w + mt*16 + q*4;
      float s0[4], b0[4];
      #pragma unroll
      for(int r=0;r<4;r++){ s0[r]=sg[ob0+r]*BNS; b0[r]=bg[ob0+r]; }
      #pragma unroll
      for(int nt=0; nt<4; nt++){
        int n = nt*16 + l15;
        size_t row = ((size_t)bm*64+n)*2*O;
        unsigned short hv[4], lv[4];
        #pragma unroll
        for(int r=0;r<4;r++){
          float v = fmaxf(acc[mt][nt][r]*s0[r]+b0[r], 0.f);
          hv[r]=f2bs(v); lv[r]=f2bs(v - bs2f(hv[r]));
        }
        *(ushort4*)(ob + row + ob0)     = make_ushort4(hv[0],hv[1],hv[2],hv[3]);
        *(ushort4*)(ob + row + O + ob0) = make_ushort4(lv[0],lv[1],lv[2],lv[3]);
      }
    }
  } else if(EPI==1){
    unsigned short* cat = (unsigned short*)Og;   // [n][2][192]
    #pragma unroll
    for(int mt=0; mt<2; mt++){
      int ob0 = o_w + mt*16 + q*4;
      float bi[4];
      #pragma unroll
      for(int r=0;r<4;r++) bi[r]=sg[ob0+r];
      #pragma unroll
      for(int nt=0; nt<4; nt++){
        int n = nt*16 + l15;
        size_t row = ((size_t)bm*64+n)*384;
        ushort4 hv = *(ushort4*)(cat + row + ob0);
        ushort4 lv = *(ushort4*)(cat + row + 192 + ob0);
        unsigned short h[4]={hv.x,hv.y,hv.z,hv.w}, l[4]={lv.x,lv.y,lv.z,lv.w};
        #pragma unroll
        for(int r=0;r<4;r++){
          float g = 1.f/(1.f+__expf(-(acc[mt][nt][r]+bi[r])));
          float f = (bs2f(h[r])+bs2f(l[r]))*g;
          h[r]=f2bs(f); l[r]=f2bs(f-bs2f(h[r]));
        }
        *(ushort4*)(cat + row + ob0)       = make_ushort4(h[0],h[1],h[2],h[3]);
        *(ushort4*)(cat + row + 192 + ob0) = make_ushort4(l[0],l[1],l[2],l[3]);
      }
    }
  } else {
    float* pool = (float*)Og;
    int b = bm>>8, m = bm&255;
    #pragma unroll
    for(int mt=0; mt<2; mt++){
      int ob0 = o_w + mt*16 + q*4;
      #pragma unroll
      for(int r=0;r<4;r++){
        float s=sg[ob0+r]*BNS, bi=bg[ob0+r];
        float v = acc[mt][0][r]*s+bi;
        v = fmaxf(v, acc[mt][1][r]*s+bi);
        v = fmaxf(v, acc[mt][2][r]*s+bi);
        v = fmaxf(v, acc[mt][3][r]*s+bi);
        v = fmaxf(v, 0.f);
        v = fmaxf(v, __shfl_xor(v,1));
        v = fmaxf(v, __shfl_xor(v,2));
        v = fmaxf(v, __shfl_xor(v,4));
        v = fmaxf(v, __shfl_xor(v,8));
        if(l15==0) pool[((size_t)b*512 + ob0+r)*256 + m] = v;
      }
    }
  }
}

// ---------------- transpose W[O][K] -> Wt[K][O] -----------------------------
__global__ __launch_bounds__(256) void k_tr(const float* __restrict__ in,
    float* __restrict__ out, int O, int K){
  __shared__ float s[32][33];
  int nt = O>>5;
  int to = blockIdx.x % nt, tk = blockIdx.x / nt;
  int c = threadIdx.x&31, r8 = threadIdx.x>>5;
  #pragma unroll
  for(int p=0;p<4;p++){
    int r = r8 + p*8;
    s[r][c] = in[(size_t)(to*32+r)*K + tk*32 + c];
  }
  __syncthreads();
  #pragma unroll
  for(int p=0;p<4;p++){
    int r = r8 + p*8;
    out[(size_t)(tk*32+r)*O + to*32 + c] = s[c][r];
  }
}

// ---------------- head GEMM (f32, LDS-tiled): Y = Wt^T @ X ------------------
// X: [b][K][256] f32. group g=b*4+mg selects 64-col window. BM=64, BK=32.
// EPI 0 (red): r=relu(acc*p0*BNS+p1); out=2r*(p2*BNS)+p3
// EPI 1 (sc1): out=relu(acc+p0)
// EPI 2 (sc2): v=res+acc+p0; out=v*(p1*BNS)+p2
template<int EPI>
__global__ __launch_bounds__(256) void k_head(const float* __restrict__ Wt,
    const float* __restrict__ Xg, float* __restrict__ Og,
    const float* __restrict__ p0, const float* __restrict__ p1,
    const float* __restrict__ p2, const float* __restrict__ p3,
    const float* __restrict__ res, int O, int K){
  __shared__ float As[32][64];
  __shared__ float Bs[32][64];
  int not_ = O>>6;
  int g = blockIdx.x / not_, ot = blockIdx.x % not_;
  int b = g>>2, mg = g&3;
  int o0 = ot*64;
  int tid=threadIdx.x, tx=tid&7, ty=tid>>3;
  float acc[2][8];
  #pragma unroll
  for(int a=0;a<2;a++)
    #pragma unroll
    for(int d=0;d<8;d++) acc[a][d]=0.f;
  const float* Xb = Xg + (size_t)b*K*256 + mg*64;
  for(int k0=0;k0<K;k0+=32){
    __syncthreads();
    #pragma unroll
    for(int p=0;p<2;p++){
      int r = p*16 + (tid>>4), c4 = (tid&15)*4;
      *(float4*)&As[r][c4] = *(const float4*)&Wt[(size_t)(k0+r)*O + o0 + c4];
      *(float4*)&Bs[r][c4] = *(const float4*)&Xb[(size_t)(k0+r)*256 + c4];
    }
    __syncthreads();
    #pragma unroll
    for(int k=0;k<32;k++){
      float av[2], bv[8];
      av[0]=As[k][ty*2]; av[1]=As[k][ty*2+1];
      #pragma unroll
      for(int d=0;d<8;d++) bv[d]=Bs[k][tx*8+d];
      #pragma unroll
      for(int a=0;a<2;a++)
        #pragma unroll
        for(int d=0;d<8;d++) acc[a][d]+=av[a]*bv[d];
    }
  }
  int m0 = mg*64 + tx*8;
  #pragma unroll
  for(int a=0;a<2;a++){
    int o=o0+ty*2+a;
    float* orow = Og + ((size_t)b*O + o)*256 + m0;
    float v[8];
    if(EPI==0){
      float s=p0[o]*BNS, bi=p1[o], s1=p2[o]*BNS, b1=p3[o];
      #pragma unroll
      for(int d=0;d<8;d++){ float r=fmaxf(acc[a][d]*s+bi,0.f); v[d]=2.f*r*s1+b1; }
    } else if(EPI==1){
      float bi=p0[o];
      #pragma unroll
      for(int d=0;d<8;d++) v[d]=fmaxf(acc[a][d]+bi,0.f);
    } else {
      float bi=p0[o], s2=p1[o]*BNS, b2=p2[o];
      const float* rr = res + ((size_t)b*O + o)*256 + m0;
      #pragma unroll
      for(int d=0;d<8;d++){ float u=rr[d]+acc[a][d]+bi; v[d]=u*s2+b2; }
    }
    *(float4*)orow     = make_float4(v[0],v[1],v[2],v[3]);
    *(float4*)(orow+4) = make_float4(v[4],v[5],v[6],v[7]);
  }
}

extern "C" void kernel_launch(void* const* d_in, const int* in_sizes, int n_in,
                              void* d_out, int out_size, void* d_ws, size_t ws_size,
                              hipStream_t stream){
  const float* xyz     =(const float*)d_in[0];
  const float* feats   =(const float*)d_in[1];
  const float* e1_w    =(const float*)d_in[2];
  const float* e1_g    =(const float*)d_in[3];
  const float* e1_b    =(const float*)d_in[4];
  const float* e2_w    =(const float*)d_in[5];
  const float* e2_g    =(const float*)d_in[6];
  const float* e2_b    =(const float*)d_in[7];
  const float* cal1_w  =(const float*)d_in[8];
  const float* cal1_g  =(const float*)d_in[9];
  const float* cal1_b  =(const float*)d_in[10];
  const float* cal2_w  =(const float*)d_in[11];
  const float* cal2_bias=(const float*)d_in[12];
  const float* exp1_w  =(const float*)d_in[13];
  const float* exp1_g  =(const float*)d_in[14];
  const float* exp1_b  =(const float*)d_in[15];
  const float* exp2_w  =(const float*)d_in[16];
  const float* exp2_g  =(const float*)d_in[17];
  const float* exp2_b  =(const float*)d_in[18];
  const float* red_w   =(const float*)d_in[19];
  const float* red_g   =(const float*)d_in[20];
  const float* red_b   =(const float*)d_in[21];
  const float* sc1_w   =(const float*)d_in[22];
  const float* sc1_b   =(const float*)d_in[23];
  const float* sc2_w   =(const float*)d_in[24];
  const float* sc2_b   =(const float*)d_in[25];
  const float* sc_n1_g =(const float*)d_in[26];
  const float* sc_n1_b =(const float*)d_in[27];
  const float* sc_n2_g =(const float*)d_in[28];
  const float* sc_n2_b =(const float*)d_in[29];

  char* wsb=(char*)d_ws;
  // layout (peak 71,303,168 B, same as proven):
  // [0,2M)        idx
  // [2M,10M)      x0s split (knn->edge1); c1s reuses (cal1->cal2)
  // [10M,34M)     cats split [n][2][192] (edge1->exp1); head Wt f32 after exp1
  // [34M,66M+..)  p1s split [n][2][256]  (exp1->exp2)
  // [69206016,70254592)  pool f32 [b][512][256]
  // [70254592,70778880)  x1 f32  | overlaid: Whi bf16 (dead before red)
  // [70778880,71303168)  hbuf f32| overlaid: Wlo bf16 tail
  int*            idx =(int*)           (wsb);
  unsigned short* x0s =(unsigned short*)(wsb + 2097152);
  unsigned short* c1s = x0s;
  unsigned short* cats=(unsigned short*)(wsb + 10485760);
  unsigned short* p1s =(unsigned short*)(wsb + 35651584);
  float*          pool=(float*)         (wsb + 69206016);
  float*          x1  =(float*)         (wsb + 70254592);
  float*          hbuf=(float*)         (wsb + 70778880);
  unsigned short* Whi =(unsigned short*)(wsb + 70254592);
  unsigned short* Wlo =(unsigned short*)(wsb + 70713344);
  // head transposed weights in dead cats region:
  float*          Wt_red=(float*)       (wsb + 10485760);            // 512x256
  float*          Wt_s1 =(float*)       (wsb + 10485760 + 524288);   // 256x256
  float*          Wt_s2 =(float*)       (wsb + 10485760 + 786432);   // 256x256
  // bf16 split W sub-offsets (ushort elements):
  unsigned short* e1e_h=Whi;          unsigned short* e1e_l=Wlo;          // 128x64
  unsigned short* e2e_h=Whi+8192;     unsigned short* e2e_l=Wlo+8192;     // 256x64
  unsigned short* c1w_h=Whi+24576;    unsigned short* c1w_l=Wlo+24576;    // 64x192
  unsigned short* c2w_h=Whi+36864;    unsigned short* c2w_l=Wlo+36864;    // 192x64
  unsigned short* e1w_h=Whi+49152;    unsigned short* e1w_l=Wlo+49152;    // 256x192
  unsigned short* e2w_h=Whi+98304;    unsigned short* e2w_l=Wlo+98304;    // 512x256

  // weight prep (independent of data path)
  k_splite    <<< 32,256,0,stream>>>(e1_w,e1e_h,e1e_l, 64);
  k_splite    <<< 64,256,0,stream>>>(e2_w,e2e_h,e2e_l,128);
  k_split     <<< 48,256,0,stream>>>(cal1_w,c1w_h,c1w_l, 12288);
  k_split     <<< 48,256,0,stream>>>(cal2_w,c2w_h,c2w_l, 12288);
  k_split     <<<192,256,0,stream>>>(exp1_w,e1w_h,e1w_l, 49152);
  k_split     <<<512,256,0,stream>>>(exp2_w,e2w_h,e2w_l,131072);
  // main pipeline
  k_knn       <<<512, 64,0,stream>>>(xyz,feats,idx,x0s);
  k_edge2< 64><<<512,256,0,stream>>>(e1e_h,e1e_l,x0s, 128, 64,idx,e1_g,e1_b,cats, 0);
  k_edge2<128><<<512,256,0,stream>>>(e2e_h,e2e_l,cats,384,192,idx,e2_g,e2_b,cats,64);
  k_mm<192,0> <<<dim3(512,1),256,0,stream>>>(c1w_h,c1w_l,cats,(void*)c1s,cal1_g,cal1_b, 64);
  k_mm< 64,1> <<<dim3(512,2),256,0,stream>>>(c2w_h,c2w_l,c1s,(void*)cats,cal2_bias,cal2_bias,192);
  k_mm<192,0> <<<dim3(512,2),256,0,stream>>>(e1w_h,e1w_l,cats,(void*)p1s,exp1_g,exp1_b,256);
  // cats dead -> stage head Wt there
  k_tr        <<<128,256,0,stream>>>(red_w,Wt_red,256,512);
  k_tr        <<< 64,256,0,stream>>>(sc1_w,Wt_s1,256,256);
  k_tr        <<< 64,256,0,stream>>>(sc2_w,Wt_s2,256,256);
  k_mm<256,2> <<<dim3(512,4),256,0,stream>>>(e2w_h,e2w_l,p1s,(void*)pool,exp2_g,exp2_b,512);
  // head: 8 col-groups x 4 o-tiles = 32 blocks each
  k_head<0>   <<< 32,256,0,stream>>>(Wt_red,pool,x1,  red_g,red_b,sc_n1_g,sc_n1_b,nullptr,256,512);
  k_head<1>   <<< 32,256,0,stream>>>(Wt_s1, x1,  hbuf,sc1_b,nullptr,nullptr,nullptr,nullptr,256,256);
  k_head<2>   <<< 32,256,0,stream>>>(Wt_s2, hbuf,(float*)d_out,sc2_b,sc_n2_g,sc_n2_b,nullptr,x1,256,256);
}

// Round 6
// 330.354 us; speedup vs baseline: 1.6199x; 1.2435x over previous
//
#include <hip/hip_runtime.h>
#include <hip/hip_bf16.h>
#include <math.h>
#include <stddef.h>

#define DEV __device__ __forceinline__
__device__ const float BNS = 0.99999500003749968f; // 1/sqrt(1+1e-5)

typedef __bf16 bf16x8 __attribute__((ext_vector_type(8)));
typedef float  f32x4  __attribute__((ext_vector_type(4)));

DEV unsigned short f2bs(float v){
  union{ __hip_bfloat16 b; unsigned short u; } c; c.b=__float2bfloat16(v); return c.u;
}
DEV float bs2f(unsigned short u){
  union{ unsigned short u; __hip_bfloat16 b; } c; c.u=u; return __bfloat162float(c.b);
}

// Geometry: B=2, M=256 -> 512 bm groups, N=64 pts, KNN=16, CIN=64,
// edge1 O=64, edge2 O=128, SUMM=192, CALIB=64, EXP=256/512, OUT=256. f32 I/O.
// Split-bf16 activation layout: [row][2][K] ushort (hi row, lo row), row=bm*64+n.

// ---------------- kernel A: knn + x0 split [n][2][64] -----------------------
__global__ __launch_bounds__(64) void k_knn(const float* __restrict__ xyz,
    const float* __restrict__ feats, int* __restrict__ idxo,
    unsigned short* __restrict__ x0s){
  int bm = blockIdx.x; int n = threadIdx.x;
  __shared__ float sx0[64], sx1[64], sx2[64], sxx[64];
  __shared__ float pd[64][65];
  __shared__ unsigned short sb[64*130];   // split staging, row stride 130
  const float* xp = xyz + (size_t)(bm*64+n)*3;
  float px=xp[0], py=xp[1], pz=xp[2];
  sx0[n]=px; sx1[n]=py; sx2[n]=pz; sxx[n]=px*px+py*py+pz*pz;
  __syncthreads();
  float xxn = sxx[n];
  for(int m=0;m<64;m++){
    float inner = px*sx0[m]+py*sx1[m]+pz*sx2[m];
    pd[n][m] = 2.0f*inner - xxn - sxx[m];
  }
  int* ip = idxo + bm*1024 + n*16;
  for(int j=0;j<16;j++){
    float best=-3.4e38f; int bi=0;
    for(int m=0;m<64;m++){ float v=pd[n][m]; if(v>best){best=v;bi=m;} }
    ip[j]=bi; pd[n][bi]=-3.4e38f;  // strict > keeps lowest index on ties (lax.top_k)
  }
  // split row n into sb
  unsigned short* r = sb + n*130;
  {
    unsigned short h;
    h=f2bs(px); r[0]=h; r[64]=f2bs(px-bs2f(h));
    h=f2bs(py); r[1]=h; r[65]=f2bs(py-bs2f(h));
    h=f2bs(pz); r[2]=h; r[66]=f2bs(pz-bs2f(h));
  }
  const float* fp = feats + (size_t)(bm*64+n)*61;
  for(int c=0;c<61;c++){
    float v=fp[c]; unsigned short h=f2bs(v);
    r[3+c]=h; r[64+3+c]=f2bs(v-bs2f(h));
  }
  __syncthreads();
  // coalesced write: 64 rows x 128 ushort = 4096 uint
  unsigned int* g32 = (unsigned int*)(x0s + (size_t)bm*8192);
  const unsigned int* s32 = (const unsigned int*)sb;
  for(int i=0;i<64;i++) g32[i*64 + n] = s32[i*65 + n];
}

// ---------------- split f32 -> bf16 hi/lo (cal/exp weights) -----------------
__global__ __launch_bounds__(256) void k_split(const float* __restrict__ in,
    unsigned short* __restrict__ hi, unsigned short* __restrict__ lo, int n){
  int i = blockIdx.x*256 + threadIdx.x;
  if(i<n){ float v=in[i]; unsigned short h=f2bs(v); hi[i]=h; lo[i]=f2bs(v-bs2f(h)); }
}

// ---------------- edge weight prep: rows [W1 ; W2-W1], split bf16 -----------
__global__ __launch_bounds__(256) void k_splite(const float* __restrict__ W,
    unsigned short* __restrict__ hi, unsigned short* __restrict__ lo, int O){
  int i = blockIdx.x*256 + threadIdx.x;   // over 2*O*64
  int row = i>>6, c = i&63;
  float v = (row<O) ? W[row*128+c] : (W[(row-O)*128+64+c] - W[(row-O)*128+c]);
  unsigned short h=f2bs(v); hi[i]=h; lo[i]=f2bs(v-bs2f(h));
}

// ---------------- edgeconv via MFMA + LDS gather ---------------------------
// Wc (split, [2O][64]): rows [0,O)=W1, [O,2O)=W2-W1.
// X split rows (bm*64+n)*RS, lo at +LO. out -> cat [n][2][192] at coloff.
// v(o,n) = max(0, s[o]*( max_k z[o,idx[n][k]] + dd[o,n] ) + b[o]),  s>0.
template<int O>
__global__ __launch_bounds__(256) void k_edge2(
    const unsigned short* __restrict__ Wh, const unsigned short* __restrict__ Wl,
    const unsigned short* __restrict__ X, int RS, int LO,
    const int* __restrict__ idxg, const float* __restrict__ gg,
    const float* __restrict__ bb, unsigned short* __restrict__ cat, int coloff){
  __shared__ float zs[64*65];
  __shared__ float ds[64*65];
  int bm = blockIdx.x;
  int tid = threadIdx.x, wid = tid>>6, lane = tid&63;
  int l15 = lane&15, q = lane>>4;
  const int* ip0 = idxg + bm*1024;
  size_t xrow = ((size_t)bm*64 + l15)*RS;
  for(int ch=0; ch<O/64; ch++){
    // MFMA: z rows (wid<2) / dd rows (wid>=2), 32 rows per wave
    int rbase = ((wid<2)?0:O) + ch*64 + (wid&1)*32;
    f32x4 acc[2][4];
    #pragma unroll
    for(int a=0;a<2;a++)
      #pragma unroll
      for(int d=0;d<4;d++) acc[a][d]=(f32x4){0.f,0.f,0.f,0.f};
    #pragma unroll
    for(int kc=0;kc<2;kc++){
      int k0=kc*32;
      size_t a0=(size_t)(rbase+l15)*64 + k0 + q*8;
      size_t a1=(size_t)(rbase+16+l15)*64 + k0 + q*8;
      bf16x8 a0h=*(const bf16x8*)(Wh+a0), a0l=*(const bf16x8*)(Wl+a0);
      bf16x8 a1h=*(const bf16x8*)(Wh+a1), a1l=*(const bf16x8*)(Wl+a1);
      #pragma unroll
      for(int nt=0;nt<4;nt++){
        const unsigned short* xp = X + xrow + (size_t)nt*16*RS + k0 + q*8;
        bf16x8 bh=*(const bf16x8*)xp, bl=*(const bf16x8*)(xp+LO);
        acc[0][nt]=__builtin_amdgcn_mfma_f32_16x16x32_bf16(a0h,bh,acc[0][nt],0,0,0);
        acc[0][nt]=__builtin_amdgcn_mfma_f32_16x16x32_bf16(a0h,bl,acc[0][nt],0,0,0);
        acc[0][nt]=__builtin_amdgcn_mfma_f32_16x16x32_bf16(a0l,bh,acc[0][nt],0,0,0);
        acc[1][nt]=__builtin_amdgcn_mfma_f32_16x16x32_bf16(a1h,bh,acc[1][nt],0,0,0);
        acc[1][nt]=__builtin_amdgcn_mfma_f32_16x16x32_bf16(a1h,bl,acc[1][nt],0,0,0);
        acc[1][nt]=__builtin_amdgcn_mfma_f32_16x16x32_bf16(a1l,bh,acc[1][nt],0,0,0);
      }
    }
    __syncthreads();   // prev chunk's gather done before overwrite
    float* dst = (wid<2)? zs : ds;
    int ro = (wid&1)*32;
    #pragma unroll
    for(int mt=0;mt<2;mt++)
      #pragma unroll
      for(int nt=0;nt<4;nt++)
        #pragma unroll
        for(int rr=0;rr<4;rr++)
          dst[(ro+mt*16+q*4+rr)*65 + nt*16+l15] = acc[mt][nt][rr];
    __syncthreads();
    // gather: lane = o (within chunk), wave wid covers n = wid*16+j
    int o = ch*64 + lane;
    float s = gg[o]*BNS, bi = bb[o];
    #pragma unroll 4
    for(int j=0;j<16;j++){
      int n = wid*16 + j;
      const int* ip = ip0 + n*16;
      float mz = -3.4e38f;
      #pragma unroll
      for(int k=0;k<16;k++) mz = fmaxf(mz, zs[lane*65 + ip[k]]);
      float v = fmaxf(s*(mz + ds[lane*65 + n]) + bi, 0.f);
      unsigned short hv = f2bs(v);
      size_t cb = ((size_t)bm*64+n)*384 + coloff + o;
      cat[cb] = hv; cat[cb+192] = f2bs(v - bs2f(hv));
    }
    __syncthreads();
  }
}

// ---------------- LDS-tiled split-bf16 MFMA GEMM ---------------------------
// C[row][o] over rows=32768 (bm*64+n). Tile: 128 rows x BO o, BK=32.
// Both tiles staged in LDS, 16B units XOR-swizzled: unit (r,u) at r*8+(u^(r&7)).
// Wave = BO/4 o-columns x all 128 rows. 3-MFMA split accumulate.
// EPI 0: write split out [row][2][O] = relu(acc*s+b)
// EPI 1: gate cat [row][2][192] *= sigmoid(acc + sg[o])
// EPI 2: pool[(b*512+o)*256+m] = max(0, max_n(acc*s+b)), bm=2*rt+half
template<int K, int BO, int EPI>
__global__ __launch_bounds__(256) void k_mm2(
    const unsigned short* __restrict__ Whi, const unsigned short* __restrict__ Wlo,
    const unsigned short* __restrict__ X, void* __restrict__ Og,
    const float* __restrict__ sg, const float* __restrict__ bg, int O){
  constexpr int WO = BO/4;        // o per wave
  constexpr int MT = WO/16;       // o-frags per wave
  constexpr int WUNITS = BO*8;    // 16B units in W tile
  __shared__ __align__(16) unsigned short sW[BO*64];
  __shared__ __align__(16) unsigned short sX[128*64];
  int rt = blockIdx.x;            // rows rt*128..+127  (bm groups 2rt, 2rt+1)
  int o0 = blockIdx.y*BO;
  int tid = threadIdx.x, wid = tid>>6, lane = tid&63;
  int l15 = lane&15, q = lane>>4;
  f32x4 acc[MT][8];
  #pragma unroll
  for(int a=0;a<MT;a++)
    #pragma unroll
    for(int d=0;d<8;d++) acc[a][d]=(f32x4){0.f,0.f,0.f,0.f};
  size_t xbase = (size_t)rt*128*2*K;
  for(int kc=0; kc<K/32; kc++){
    int k0 = kc*32;
    __syncthreads();
    // stage W tile: BO rows x 64 ushort (32 hi | 32 lo), swizzled
    #pragma unroll
    for(int i=0;i<WUNITS/256;i++){
      int U = tid + i*256;
      int r = U>>3, up = U&7, u = up ^ (r&7);
      const unsigned short* src = (u<4)
        ? (Whi + (size_t)(o0+r)*K + k0 + u*8)
        : (Wlo + (size_t)(o0+r)*K + k0 + (u-4)*8);
      *(uint4*)&sW[U*8] = *(const uint4*)src;
    }
    // stage X tile: 128 rows x 64 ushort, swizzled
    #pragma unroll
    for(int i=0;i<4;i++){
      int U = tid + i*256;
      int r = U>>3, up = U&7, u = up ^ (r&7);
      const unsigned short* src = X + xbase + (size_t)r*2*K
        + (u<4 ? (size_t)(k0 + u*8) : (size_t)(K + k0 + (u-4)*8));
      *(uint4*)&sX[U*8] = *(const uint4*)src;
    }
    __syncthreads();
    bf16x8 wf[MT][2];
    #pragma unroll
    for(int mt=0;mt<MT;mt++){
      int o = wid*WO + mt*16 + l15;
      wf[mt][0] = *(const bf16x8*)&sW[(o*8 + ((  q) ^ (o&7)))*8];
      wf[mt][1] = *(const bf16x8*)&sW[(o*8 + ((4+q) ^ (o&7)))*8];
    }
    #pragma unroll
    for(int nf=0;nf<8;nf++){
      int r = nf*16 + l15;
      bf16x8 xh = *(const bf16x8*)&sX[(r*8 + ((  q) ^ (r&7)))*8];
      bf16x8 xl = *(const bf16x8*)&sX[(r*8 + ((4+q) ^ (r&7)))*8];
      #pragma unroll
      for(int mt=0;mt<MT;mt++){
        acc[mt][nf]=__builtin_amdgcn_mfma_f32_16x16x32_bf16(wf[mt][0],xh,acc[mt][nf],0,0,0);
        acc[mt][nf]=__builtin_amdgcn_mfma_f32_16x16x32_bf16(wf[mt][0],xl,acc[mt][nf],0,0,0);
        acc[mt][nf]=__builtin_amdgcn_mfma_f32_16x16x32_bf16(wf[mt][1],xh,acc[mt][nf],0,0,0);
      }
    }
  }
  // C/D: col(n)=l15, row(o)=q*4+reg  [m89]
  if(EPI==0){
    unsigned short* ob = (unsigned short*)Og;
    #pragma unroll
    for(int mt=0;mt<MT;mt++){
      int ob0 = o0 + wid*WO + mt*16 + q*4;
      float s0[4], b0[4];
      #pragma unroll
      for(int r=0;r<4;r++){ s0[r]=sg[ob0+r]*BNS; b0[r]=bg[ob0+r]; }
      #pragma unroll
      for(int nf=0;nf<8;nf++){
        size_t row = (size_t)rt*128 + nf*16 + l15;
        size_t rb = row*2*O;
        unsigned short hv[4], lv[4];
        #pragma unroll
        for(int r=0;r<4;r++){
          float v = fmaxf(acc[mt][nf][r]*s0[r]+b0[r], 0.f);
          hv[r]=f2bs(v); lv[r]=f2bs(v - bs2f(hv[r]));
        }
        *(ushort4*)(ob + rb + ob0)     = make_ushort4(hv[0],hv[1],hv[2],hv[3]);
        *(ushort4*)(ob + rb + O + ob0) = make_ushort4(lv[0],lv[1],lv[2],lv[3]);
      }
    }
  } else if(EPI==1){
    unsigned short* cat = (unsigned short*)Og;   // [row][2][192]
    #pragma unroll
    for(int mt=0;mt<MT;mt++){
      int ob0 = o0 + wid*WO + mt*16 + q*4;
      float bi[4];
      #pragma unroll
      for(int r=0;r<4;r++) bi[r]=sg[ob0+r];
      #pragma unroll
      for(int nf=0;nf<8;nf++){
        size_t row = (size_t)rt*128 + nf*16 + l15;
        size_t rb = row*384;
        ushort4 hv = *(ushort4*)(cat + rb + ob0);
        ushort4 lv = *(ushort4*)(cat + rb + 192 + ob0);
        unsigned short h[4]={hv.x,hv.y,hv.z,hv.w}, l[4]={lv.x,lv.y,lv.z,lv.w};
        #pragma unroll
        for(int r=0;r<4;r++){
          float g = 1.f/(1.f+__expf(-(acc[mt][nf][r]+bi[r])));
          float f = (bs2f(h[r])+bs2f(l[r]))*g;
          h[r]=f2bs(f); l[r]=f2bs(f-bs2f(h[r]));
        }
        *(ushort4*)(cat + rb + ob0)       = make_ushort4(h[0],h[1],h[2],h[3]);
        *(ushort4*)(cat + rb + 192 + ob0) = make_ushort4(l[0],l[1],l[2],l[3]);
      }
    }
  } else {
    float* pool = (float*)Og;
    #pragma unroll
    for(int mt=0;mt<MT;mt++){
      int ob0 = o0 + wid*WO + mt*16 + q*4;
      #pragma unroll
      for(int half=0;half<2;half++){
        int bm = 2*rt + half;
        int b = bm>>8, m = bm&255;
        #pragma unroll
        for(int r=0;r<4;r++){
          float s=sg[ob0+r]*BNS, bi=bg[ob0+r];
          float v = acc[mt][half*4+0][r]*s+bi;
          v = fmaxf(v, acc[mt][half*4+1][r]*s+bi);
          v = fmaxf(v, acc[mt][half*4+2][r]*s+bi);
          v = fmaxf(v, acc[mt][half*4+3][r]*s+bi);
          v = fmaxf(v, 0.f);
          v = fmaxf(v, __shfl_xor(v,1));
          v = fmaxf(v, __shfl_xor(v,2));
          v = fmaxf(v, __shfl_xor(v,4));
          v = fmaxf(v, __shfl_xor(v,8));
          if(l15==0) pool[((size_t)b*512 + ob0+r)*256 + m] = v;
        }
      }
    }
  }
}

// ---------------- transpose W[O][K] -> Wt[K][O] -----------------------------
__global__ __launch_bounds__(256) void k_tr(const float* __restrict__ in,
    float* __restrict__ out, int O, int K){
  __shared__ float s[32][33];
  int nt = O>>5;
  int to = blockIdx.x % nt, tk = blockIdx.x / nt;
  int c = threadIdx.x&31, r8 = threadIdx.x>>5;
  #pragma unroll
  for(int p=0;p<4;p++){
    int r = r8 + p*8;
    s[r][c] = in[(size_t)(to*32+r)*K + tk*32 + c];
  }
  __syncthreads();
  #pragma unroll
  for(int p=0;p<4;p++){
    int r = r8 + p*8;
    out[(size_t)(tk*32+r)*O + to*32 + c] = s[c][r];
  }
}

// ---------------- head GEMM (f32, LDS-tiled): Y = Wt^T @ X ------------------
template<int EPI>
__global__ __launch_bounds__(256) void k_head(const float* __restrict__ Wt,
    const float* __restrict__ Xg, float* __restrict__ Og,
    const float* __restrict__ p0, const float* __restrict__ p1,
    const float* __restrict__ p2, const float* __restrict__ p3,
    const float* __restrict__ res, int O, int K){
  __shared__ float As[32][64];
  __shared__ float Bs[32][64];
  int not_ = O>>6;
  int g = blockIdx.x / not_, ot = blockIdx.x % not_;
  int b = g>>2, mg = g&3;
  int o0 = ot*64;
  int tid=threadIdx.x, tx=tid&7, ty=tid>>3;
  float acc[2][8];
  #pragma unroll
  for(int a=0;a<2;a++)
    #pragma unroll
    for(int d=0;d<8;d++) acc[a][d]=0.f;
  const float* Xb = Xg + (size_t)b*K*256 + mg*64;
  for(int k0=0;k0<K;k0+=32){
    __syncthreads();
    #pragma unroll
    for(int p=0;p<2;p++){
      int r = p*16 + (tid>>4), c4 = (tid&15)*4;
      *(float4*)&As[r][c4] = *(const float4*)&Wt[(size_t)(k0+r)*O + o0 + c4];
      *(float4*)&Bs[r][c4] = *(const float4*)&Xb[(size_t)(k0+r)*256 + c4];
    }
    __syncthreads();
    #pragma unroll
    for(int k=0;k<32;k++){
      float av[2], bv[8];
      av[0]=As[k][ty*2]; av[1]=As[k][ty*2+1];
      #pragma unroll
      for(int d=0;d<8;d++) bv[d]=Bs[k][tx*8+d];
      #pragma unroll
      for(int a=0;a<2;a++)
        #pragma unroll
        for(int d=0;d<8;d++) acc[a][d]+=av[a]*bv[d];
    }
  }
  int m0 = mg*64 + tx*8;
  #pragma unroll
  for(int a=0;a<2;a++){
    int o=o0+ty*2+a;
    float* orow = Og + ((size_t)b*O + o)*256 + m0;
    float v[8];
    if(EPI==0){
      float s=p0[o]*BNS, bi=p1[o], s1=p2[o]*BNS, b1=p3[o];
      #pragma unroll
      for(int d=0;d<8;d++){ float r=fmaxf(acc[a][d]*s+bi,0.f); v[d]=2.f*r*s1+b1; }
    } else if(EPI==1){
      float bi=p0[o];
      #pragma unroll
      for(int d=0;d<8;d++) v[d]=fmaxf(acc[a][d]+bi,0.f);
    } else {
      float bi=p0[o], s2=p1[o]*BNS, b2=p2[o];
      const float* rr = res + ((size_t)b*O + o)*256 + m0;
      #pragma unroll
      for(int d=0;d<8;d++){ float u=rr[d]+acc[a][d]+bi; v[d]=u*s2+b2; }
    }
    *(float4*)orow     = make_float4(v[0],v[1],v[2],v[3]);
    *(float4*)(orow+4) = make_float4(v[4],v[5],v[6],v[7]);
  }
}

extern "C" void kernel_launch(void* const* d_in, const int* in_sizes, int n_in,
                              void* d_out, int out_size, void* d_ws, size_t ws_size,
                              hipStream_t stream){
  const float* xyz     =(const float*)d_in[0];
  const float* feats   =(const float*)d_in[1];
  const float* e1_w    =(const float*)d_in[2];
  const float* e1_g    =(const float*)d_in[3];
  const float* e1_b    =(const float*)d_in[4];
  const float* e2_w    =(const float*)d_in[5];
  const float* e2_g    =(const float*)d_in[6];
  const float* e2_b    =(const float*)d_in[7];
  const float* cal1_w  =(const float*)d_in[8];
  const float* cal1_g  =(const float*)d_in[9];
  const float* cal1_b  =(const float*)d_in[10];
  const float* cal2_w  =(const float*)d_in[11];
  const float* cal2_bias=(const float*)d_in[12];
  const float* exp1_w  =(const float*)d_in[13];
  const float* exp1_g  =(const float*)d_in[14];
  const float* exp1_b  =(const float*)d_in[15];
  const float* exp2_w  =(const float*)d_in[16];
  const float* exp2_g  =(const float*)d_in[17];
  const float* exp2_b  =(const float*)d_in[18];
  const float* red_w   =(const float*)d_in[19];
  const float* red_g   =(const float*)d_in[20];
  const float* red_b   =(const float*)d_in[21];
  const float* sc1_w   =(const float*)d_in[22];
  const float* sc1_b   =(const float*)d_in[23];
  const float* sc2_w   =(const float*)d_in[24];
  const float* sc2_b   =(const float*)d_in[25];
  const float* sc_n1_g =(const float*)d_in[26];
  const float* sc_n1_b =(const float*)d_in[27];
  const float* sc_n2_g =(const float*)d_in[28];
  const float* sc_n2_b =(const float*)d_in[29];

  char* wsb=(char*)d_ws;
  // layout (peak 71,303,168 B):
  // [0,2M)        idx
  // [2M,10M)      x0s split (knn->edge1); c1s reuses (cal1->cal2)
  // [10M,34M)     cats split [n][2][192] (edge1->exp1); head Wt f32 after exp1
  // [34M,66M)     p1s split [n][2][256]  (exp1->exp2)
  // [69206016..)  pool f32 [b][512][256]
  // [70254592..)  x1 f32  | overlaid: Whi bf16 (dead before k_head<0>)
  // [70778880..)  hbuf f32| overlaid: Wlo bf16 tail
  int*            idx =(int*)           (wsb);
  unsigned short* x0s =(unsigned short*)(wsb + 2097152);
  unsigned short* c1s = x0s;
  unsigned short* cats=(unsigned short*)(wsb + 10485760);
  unsigned short* p1s =(unsigned short*)(wsb + 35651584);
  float*          pool=(float*)         (wsb + 69206016);
  float*          x1  =(float*)         (wsb + 70254592);
  float*          hbuf=(float*)         (wsb + 70778880);
  unsigned short* Whi =(unsigned short*)(wsb + 70254592);
  unsigned short* Wlo =(unsigned short*)(wsb + 70713344);
  float*          Wt_red=(float*)       (wsb + 10485760);            // 512x256
  float*          Wt_s1 =(float*)       (wsb + 10485760 + 524288);   // 256x256
  float*          Wt_s2 =(float*)       (wsb + 10485760 + 786432);   // 256x256
  unsigned short* e1e_h=Whi;          unsigned short* e1e_l=Wlo;          // 128x64
  unsigned short* e2e_h=Whi+8192;     unsigned short* e2e_l=Wlo+8192;     // 256x64
  unsigned short* c1w_h=Whi+24576;    unsigned short* c1w_l=Wlo+24576;    // 64x192
  unsigned short* c2w_h=Whi+36864;    unsigned short* c2w_l=Wlo+36864;    // 192x64
  unsigned short* e1w_h=Whi+49152;    unsigned short* e1w_l=Wlo+49152;    // 256x192
  unsigned short* e2w_h=Whi+98304;    unsigned short* e2w_l=Wlo+98304;    // 512x256

  // weight prep (independent of data path)
  k_splite    <<< 32,256,0,stream>>>(e1_w,e1e_h,e1e_l, 64);
  k_splite    <<< 64,256,0,stream>>>(e2_w,e2e_h,e2e_l,128);
  k_split     <<< 48,256,0,stream>>>(cal1_w,c1w_h,c1w_l, 12288);
  k_split     <<< 48,256,0,stream>>>(cal2_w,c2w_h,c2w_l, 12288);
  k_split     <<<192,256,0,stream>>>(exp1_w,e1w_h,e1w_l, 49152);
  k_split     <<<512,256,0,stream>>>(exp2_w,e2w_h,e2w_l,131072);
  // main pipeline
  k_knn       <<<512, 64,0,stream>>>(xyz,feats,idx,x0s);
  k_edge2< 64><<<512,256,0,stream>>>(e1e_h,e1e_l,x0s, 128, 64,idx,e1_g,e1_b,cats, 0);
  k_edge2<128><<<512,256,0,stream>>>(e2e_h,e2e_l,cats,384,192,idx,e2_g,e2_b,cats,64);
  // mid GEMMs: rows tiled 128 (256 row-blocks), o tiled BO
  k_mm2<192, 64,0><<<dim3(256,1),256,0,stream>>>(c1w_h,c1w_l,cats,(void*)c1s,cal1_g,cal1_b, 64);
  k_mm2< 64, 64,1><<<dim3(256,3),256,0,stream>>>(c2w_h,c2w_l,c1s,(void*)cats,cal2_bias,cal2_bias,192);
  k_mm2<192,128,0><<<dim3(256,2),256,0,stream>>>(e1w_h,e1w_l,cats,(void*)p1s,exp1_g,exp1_b,256);
  // cats dead -> stage head Wt there
  k_tr        <<<128,256,0,stream>>>(red_w,Wt_red,256,512);
  k_tr        <<< 64,256,0,stream>>>(sc1_w,Wt_s1,256,256);
  k_tr        <<< 64,256,0,stream>>>(sc2_w,Wt_s2,256,256);
  k_mm2<256,128,2><<<dim3(256,4),256,0,stream>>>(e2w_h,e2w_l,p1s,(void*)pool,exp2_g,exp2_b,512);
  // head: 8 col-groups x 4 o-tiles = 32 blocks each
  k_head<0>   <<< 32,256,0,stream>>>(Wt_red,pool,x1,  red_g,red_b,sc_n1_g,sc_n1_b,nullptr,256,512);
  k_head<1>   <<< 32,256,0,stream>>>(Wt_s1, x1,  hbuf,sc1_b,nullptr,nullptr,nullptr,nullptr,256,256);
  k_head<2>   <<< 32,256,0,stream>>>(Wt_s2, hbuf,(float*)d_out,sc2_b,sc_n2_g,sc_n2_b,nullptr,x1,256,256);
}

// Round 7
// 295.816 us; speedup vs baseline: 1.8090x; 1.1168x over previous
//
#include <hip/hip_runtime.h>
#include <hip/hip_bf16.h>
#include <math.h>
#include <stddef.h>

#define DEV __device__ __forceinline__
__device__ const float BNS = 0.99999500003749968f; // 1/sqrt(1+1e-5)

typedef __bf16 bf16x8 __attribute__((ext_vector_type(8)));
typedef float  f32x4  __attribute__((ext_vector_type(4)));

DEV unsigned short f2bs(float v){
  union{ __hip_bfloat16 b; unsigned short u; } c; c.b=__float2bfloat16(v); return c.u;
}
DEV float bs2f(unsigned short u){
  union{ unsigned short u; __hip_bfloat16 b; } c; c.u=u; return __bfloat162float(c.b);
}

// Geometry: B=2, M=256 -> 512 bm groups, N=64 pts, KNN=16, CIN=64,
// edge1 O=64, edge2 O=128, SUMM=192, CALIB=64, EXP=256/512, OUT=256. f32 I/O.
// Split-bf16 activation layout: [row][2][K] ushort (hi row, lo row), row=bm*64+n.

// ---------------- fused weight prep: all 6 split jobs in one launch ---------
__global__ __launch_bounds__(256) void k_prep(const float* __restrict__ e1_w,
    const float* __restrict__ e2_w, const float* __restrict__ cal1_w,
    const float* __restrict__ cal2_w, const float* __restrict__ exp1_w,
    const float* __restrict__ exp2_w, unsigned short* __restrict__ Whi,
    unsigned short* __restrict__ Wlo){
  int bid = blockIdx.x;
  const float* src; unsigned short *hi,*lo; int mode, O=0, i0;
  if(bid<32)      { src=e1_w;  hi=Whi;       lo=Wlo;       mode=1; O= 64; i0=bid*256; }
  else if(bid<96) { src=e2_w;  hi=Whi+8192;  lo=Wlo+8192;  mode=1; O=128; i0=(bid-32)*256; }
  else if(bid<144){ src=cal1_w;hi=Whi+24576; lo=Wlo+24576; mode=0;        i0=(bid-96)*256; }
  else if(bid<192){ src=cal2_w;hi=Whi+36864; lo=Wlo+36864; mode=0;        i0=(bid-144)*256; }
  else if(bid<384){ src=exp1_w;hi=Whi+49152; lo=Wlo+49152; mode=0;        i0=(bid-192)*256; }
  else            { src=exp2_w;hi=Whi+98304; lo=Wlo+98304; mode=0;        i0=(bid-384)*256; }
  int i = i0 + threadIdx.x;
  float v;
  if(mode==0) v = src[i];
  else { // edge rows: [W1 ; W2-W1] over [2O][64]
    int row=i>>6, c=i&63;
    v = (row<O) ? src[row*128+c] : (src[(row-O)*128+64+c]-src[(row-O)*128+c]);
  }
  unsigned short h=f2bs(v); hi[i]=h; lo[i]=f2bs(v-bs2f(h));
}

// ---------------- kernel A: knn + x0 split, 256 threads ---------------------
__global__ __launch_bounds__(256) void k_knn(const float* __restrict__ xyz,
    const float* __restrict__ feats, int* __restrict__ idxo,
    unsigned short* __restrict__ x0s){
  int bm = blockIdx.x;
  int tid = threadIdx.x, n = tid&63, s = tid>>6;   // 4 segments per point
  __shared__ float sx0[64], sx1[64], sx2[64], sxx[64];
  __shared__ float pd[64][65];
  __shared__ float cv[64][4];
  __shared__ int   ci[64][4];
  __shared__ unsigned short sb[64*130];
  if(s==0){
    const float* xp = xyz + (size_t)(bm*64+n)*3;
    float px=xp[0], py=xp[1], pz=xp[2];
    sx0[n]=px; sx1[n]=py; sx2[n]=pz; sxx[n]=px*px+py*py+pz*pz;
  }
  __syncthreads();
  float px=sx0[n], py=sx1[n], pz=sx2[n], xxn=sxx[n];
  #pragma unroll
  for(int t=0;t<16;t++){
    int m = s*16+t;
    float inner = px*sx0[m]+py*sx1[m]+pz*sx2[m];
    pd[n][m] = 2.0f*inner - xxn - sxx[m];
  }
  __syncthreads();
  int* ip = idxo + bm*1024 + n*16;
  for(int j=0;j<16;j++){
    float best=-3.4e38f; int bi=s*16;
    #pragma unroll
    for(int t=0;t<16;t++){ int m=s*16+t; float v=pd[n][m]; if(v>best){best=v;bi=m;} }
    cv[n][s]=best; ci[n][s]=bi;
    __syncthreads();
    if(s==0){
      float bb=cv[n][0]; int bj=ci[n][0];
      #pragma unroll
      for(int q2=1;q2<4;q2++){ if(cv[n][q2]>bb){bb=cv[n][q2]; bj=ci[n][q2];} }
      ip[j]=bj; pd[n][bj]=-3.4e38f;  // ascending segs + strict > == lowest-index tie (lax.top_k)
    }
    __syncthreads();
  }
  // split row n into sb (stride 130)
  unsigned short* r = sb + n*130;
  if(s==0){
    unsigned short h;
    h=f2bs(px); r[0]=h; r[64]=f2bs(px-bs2f(h));
    h=f2bs(py); r[1]=h; r[65]=f2bs(py-bs2f(h));
    h=f2bs(pz); r[2]=h; r[66]=f2bs(pz-bs2f(h));
  }
  const float* fp = feats + (size_t)(bm*64+n)*61;
  #pragma unroll
  for(int t=0;t<16;t++){
    int cc = s*16+t;
    if(cc<61){
      float v=fp[cc]; unsigned short h=f2bs(v);
      r[3+cc]=h; r[64+3+cc]=f2bs(v-bs2f(h));
    }
  }
  __syncthreads();
  unsigned int* g32 = (unsigned int*)(x0s + (size_t)bm*8192);
  const unsigned int* s32 = (const unsigned int*)sb;
  #pragma unroll
  for(int t=0;t<16;t++){ int i=s*16+t; g32[i*64+n]=s32[i*65+n]; }
}

// ---------------- edgeconv via MFMA + LDS gather ---------------------------
// Wc (split, [2O][64]): rows [0,O)=W1, [O,2O)=W2-W1.
// X split rows (bm*64+n)*RS, lo at +LO. out -> cat [n][2][192] at coloff.
// v(o,n) = max(0, s[o]*( max_k z[o,idx[n][k]] + dd[o,n] ) + b[o]).
template<int O>
__global__ __launch_bounds__(256) void k_edge2(
    const unsigned short* __restrict__ Wh, const unsigned short* __restrict__ Wl,
    const unsigned short* __restrict__ X, int RS, int LO,
    const int* __restrict__ idxg, const float* __restrict__ gg,
    const float* __restrict__ bb, unsigned short* __restrict__ cat, int coloff){
  __shared__ float zs[64*65];
  __shared__ float ds[64*65];
  int bm = blockIdx.x;
  int tid = threadIdx.x, wid = tid>>6, lane = tid&63;
  int l15 = lane&15, q = lane>>4;
  const int* ip0 = idxg + bm*1024;
  size_t xrow = ((size_t)bm*64 + l15)*RS;
  for(int ch=0; ch<O/64; ch++){
    int rbase = ((wid<2)?0:O) + ch*64 + (wid&1)*32;
    f32x4 acc[2][4];
    #pragma unroll
    for(int a=0;a<2;a++)
      #pragma unroll
      for(int d=0;d<4;d++) acc[a][d]=(f32x4){0.f,0.f,0.f,0.f};
    #pragma unroll
    for(int kc=0;kc<2;kc++){
      int k0=kc*32;
      size_t a0=(size_t)(rbase+l15)*64 + k0 + q*8;
      size_t a1=(size_t)(rbase+16+l15)*64 + k0 + q*8;
      bf16x8 a0h=*(const bf16x8*)(Wh+a0), a0l=*(const bf16x8*)(Wl+a0);
      bf16x8 a1h=*(const bf16x8*)(Wh+a1), a1l=*(const bf16x8*)(Wl+a1);
      #pragma unroll
      for(int nt=0;nt<4;nt++){
        const unsigned short* xp = X + xrow + (size_t)nt*16*RS + k0 + q*8;
        bf16x8 bh=*(const bf16x8*)xp, bl=*(const bf16x8*)(xp+LO);
        acc[0][nt]=__builtin_amdgcn_mfma_f32_16x16x32_bf16(a0h,bh,acc[0][nt],0,0,0);
        acc[0][nt]=__builtin_amdgcn_mfma_f32_16x16x32_bf16(a0h,bl,acc[0][nt],0,0,0);
        acc[0][nt]=__builtin_amdgcn_mfma_f32_16x16x32_bf16(a0l,bh,acc[0][nt],0,0,0);
        acc[1][nt]=__builtin_amdgcn_mfma_f32_16x16x32_bf16(a1h,bh,acc[1][nt],0,0,0);
        acc[1][nt]=__builtin_amdgcn_mfma_f32_16x16x32_bf16(a1h,bl,acc[1][nt],0,0,0);
        acc[1][nt]=__builtin_amdgcn_mfma_f32_16x16x32_bf16(a1l,bh,acc[1][nt],0,0,0);
      }
    }
    __syncthreads();
    float* dst = (wid<2)? zs : ds;
    int ro = (wid&1)*32;
    #pragma unroll
    for(int mt=0;mt<2;mt++)
      #pragma unroll
      for(int nt=0;nt<4;nt++)
        #pragma unroll
        for(int rr=0;rr<4;rr++)
          dst[(ro+mt*16+q*4+rr)*65 + nt*16+l15] = acc[mt][nt][rr];
    __syncthreads();
    int o = ch*64 + lane;
    float s = gg[o]*BNS, bi = bb[o];
    #pragma unroll 4
    for(int j=0;j<16;j++){
      int n = wid*16 + j;
      const int* ip = ip0 + n*16;
      float mz = -3.4e38f;
      #pragma unroll
      for(int k=0;k<16;k++) mz = fmaxf(mz, zs[lane*65 + ip[k]]);
      float v = fmaxf(s*(mz + ds[lane*65 + n]) + bi, 0.f);
      unsigned short hv = f2bs(v);
      size_t cb = ((size_t)bm*64+n)*384 + coloff + o;
      cat[cb] = hv; cat[cb+192] = f2bs(v - bs2f(hv));
    }
    __syncthreads();
  }
}

// ---------------- LDS-tiled split-bf16 MFMA GEMM ---------------------------
// Tile: 128 rows x BO o, BK=32; XOR-swizzled 16B units in LDS.
template<int K, int BO, int EPI>
__global__ __launch_bounds__(256) void k_mm2(
    const unsigned short* __restrict__ Whi, const unsigned short* __restrict__ Wlo,
    const unsigned short* __restrict__ X, void* __restrict__ Og,
    const float* __restrict__ sg, const float* __restrict__ bg, int O){
  constexpr int WO = BO/4;
  constexpr int MT = WO/16;
  constexpr int WUNITS = BO*8;
  __shared__ __align__(16) unsigned short sW[BO*64];
  __shared__ __align__(16) unsigned short sX[128*64];
  int rt = blockIdx.x;
  int o0 = blockIdx.y*BO;
  int tid = threadIdx.x, wid = tid>>6, lane = tid&63;
  int l15 = lane&15, q = lane>>4;
  f32x4 acc[MT][8];
  #pragma unroll
  for(int a=0;a<MT;a++)
    #pragma unroll
    for(int d=0;d<8;d++) acc[a][d]=(f32x4){0.f,0.f,0.f,0.f};
  size_t xbase = (size_t)rt*128*2*K;
  for(int kc=0; kc<K/32; kc++){
    int k0 = kc*32;
    __syncthreads();
    #pragma unroll
    for(int i=0;i<WUNITS/256;i++){
      int U = tid + i*256;
      int r = U>>3, up = U&7, u = up ^ (r&7);
      const unsigned short* src = (u<4)
        ? (Whi + (size_t)(o0+r)*K + k0 + u*8)
        : (Wlo + (size_t)(o0+r)*K + k0 + (u-4)*8);
      *(uint4*)&sW[U*8] = *(const uint4*)src;
    }
    #pragma unroll
    for(int i=0;i<4;i++){
      int U = tid + i*256;
      int r = U>>3, up = U&7, u = up ^ (r&7);
      const unsigned short* src = X + xbase + (size_t)r*2*K
        + (u<4 ? (size_t)(k0 + u*8) : (size_t)(K + k0 + (u-4)*8));
      *(uint4*)&sX[U*8] = *(const uint4*)src;
    }
    __syncthreads();
    bf16x8 wf[MT][2];
    #pragma unroll
    for(int mt=0;mt<MT;mt++){
      int o = wid*WO + mt*16 + l15;
      wf[mt][0] = *(const bf16x8*)&sW[(o*8 + ((  q) ^ (o&7)))*8];
      wf[mt][1] = *(const bf16x8*)&sW[(o*8 + ((4+q) ^ (o&7)))*8];
    }
    #pragma unroll
    for(int nf=0;nf<8;nf++){
      int r = nf*16 + l15;
      bf16x8 xh = *(const bf16x8*)&sX[(r*8 + ((  q) ^ (r&7)))*8];
      bf16x8 xl = *(const bf16x8*)&sX[(r*8 + ((4+q) ^ (r&7)))*8];
      #pragma unroll
      for(int mt=0;mt<MT;mt++){
        acc[mt][nf]=__builtin_amdgcn_mfma_f32_16x16x32_bf16(wf[mt][0],xh,acc[mt][nf],0,0,0);
        acc[mt][nf]=__builtin_amdgcn_mfma_f32_16x16x32_bf16(wf[mt][0],xl,acc[mt][nf],0,0,0);
        acc[mt][nf]=__builtin_amdgcn_mfma_f32_16x16x32_bf16(wf[mt][1],xh,acc[mt][nf],0,0,0);
      }
    }
  }
  if(EPI==0){
    unsigned short* ob = (unsigned short*)Og;
    #pragma unroll
    for(int mt=0;mt<MT;mt++){
      int ob0 = o0 + wid*WO + mt*16 + q*4;
      float s0[4], b0[4];
      #pragma unroll
      for(int r=0;r<4;r++){ s0[r]=sg[ob0+r]*BNS; b0[r]=bg[ob0+r]; }
      #pragma unroll
      for(int nf=0;nf<8;nf++){
        size_t row = (size_t)rt*128 + nf*16 + l15;
        size_t rb = row*2*O;
        unsigned short hv[4], lv[4];
        #pragma unroll
        for(int r=0;r<4;r++){
          float v = fmaxf(acc[mt][nf][r]*s0[r]+b0[r], 0.f);
          hv[r]=f2bs(v); lv[r]=f2bs(v - bs2f(hv[r]));
        }
        *(ushort4*)(ob + rb + ob0)     = make_ushort4(hv[0],hv[1],hv[2],hv[3]);
        *(ushort4*)(ob + rb + O + ob0) = make_ushort4(lv[0],lv[1],lv[2],lv[3]);
      }
    }
  } else if(EPI==1){
    unsigned short* cat = (unsigned short*)Og;
    #pragma unroll
    for(int mt=0;mt<MT;mt++){
      int ob0 = o0 + wid*WO + mt*16 + q*4;
      float bi[4];
      #pragma unroll
      for(int r=0;r<4;r++) bi[r]=sg[ob0+r];
      #pragma unroll
      for(int nf=0;nf<8;nf++){
        size_t row = (size_t)rt*128 + nf*16 + l15;
        size_t rb = row*384;
        ushort4 hv = *(ushort4*)(cat + rb + ob0);
        ushort4 lv = *(ushort4*)(cat + rb + 192 + ob0);
        unsigned short h[4]={hv.x,hv.y,hv.z,hv.w}, l[4]={lv.x,lv.y,lv.z,lv.w};
        #pragma unroll
        for(int r=0;r<4;r++){
          float g = 1.f/(1.f+__expf(-(acc[mt][nf][r]+bi[r])));
          float f = (bs2f(h[r])+bs2f(l[r]))*g;
          h[r]=f2bs(f); l[r]=f2bs(f-bs2f(h[r]));
        }
        *(ushort4*)(cat + rb + ob0)       = make_ushort4(h[0],h[1],h[2],h[3]);
        *(ushort4*)(cat + rb + 192 + ob0) = make_ushort4(l[0],l[1],l[2],l[3]);
      }
    }
  } else {
    float* pool = (float*)Og;
    #pragma unroll
    for(int mt=0;mt<MT;mt++){
      int ob0 = o0 + wid*WO + mt*16 + q*4;
      #pragma unroll
      for(int half=0;half<2;half++){
        int bm = 2*rt + half;
        int b = bm>>8, m = bm&255;
        #pragma unroll
        for(int r=0;r<4;r++){
          float s=sg[ob0+r]*BNS, bi=bg[ob0+r];
          float v = acc[mt][half*4+0][r]*s+bi;
          v = fmaxf(v, acc[mt][half*4+1][r]*s+bi);
          v = fmaxf(v, acc[mt][half*4+2][r]*s+bi);
          v = fmaxf(v, acc[mt][half*4+3][r]*s+bi);
          v = fmaxf(v, 0.f);
          v = fmaxf(v, __shfl_xor(v,1));
          v = fmaxf(v, __shfl_xor(v,2));
          v = fmaxf(v, __shfl_xor(v,4));
          v = fmaxf(v, __shfl_xor(v,8));
          if(l15==0) pool[((size_t)b*512 + ob0+r)*256 + m] = v;
        }
      }
    }
  }
}

// ---------------- fused transposes for head weights -------------------------
__global__ __launch_bounds__(256) void k_tr3(const float* __restrict__ red_w,
    const float* __restrict__ sc1_w, const float* __restrict__ sc2_w,
    float* __restrict__ Wt_red, float* __restrict__ Wt_s1, float* __restrict__ Wt_s2){
  __shared__ float s[32][33];
  int bid=blockIdx.x;
  const float* in; float* out; int O,K,lb;
  if(bid<128){ in=red_w; out=Wt_red; O=256; K=512; lb=bid; }
  else if(bid<192){ in=sc1_w; out=Wt_s1; O=256; K=256; lb=bid-128; }
  else { in=sc2_w; out=Wt_s2; O=256; K=256; lb=bid-192; }
  int nt=O>>5;
  int to=lb%nt, tk=lb/nt;
  int c=threadIdx.x&31, r8=threadIdx.x>>5;
  #pragma unroll
  for(int p=0;p<4;p++){
    int r=r8+p*8;
    s[r][c]=in[(size_t)(to*32+r)*K + tk*32 + c];
  }
  __syncthreads();
  #pragma unroll
  for(int p=0;p<4;p++){
    int r=r8+p*8;
    out[(size_t)(tk*32+r)*O + to*32 + c]=s[c][r];
  }
}

// ---------------- head GEMM (f32, LDS-tiled, BN=32): Y = Wt^T @ X -----------
// grid = 16 col-groups (b*8+mg, 32 cols each) x (O/64) o-tiles.
template<int EPI>
__global__ __launch_bounds__(256) void k_head(const float* __restrict__ Wt,
    const float* __restrict__ Xg, float* __restrict__ Og,
    const float* __restrict__ p0, const float* __restrict__ p1,
    const float* __restrict__ p2, const float* __restrict__ p3,
    const float* __restrict__ res, int O, int K){
  __shared__ float As[32][64];
  __shared__ float Bs[32][32];
  int not_ = O>>6;
  int g = blockIdx.x / not_, ot = blockIdx.x % not_;
  int b = g>>3, mg = g&7;
  int o0 = ot*64;
  int tid=threadIdx.x, tx=tid&7, ty=tid>>3;
  float acc[2][4];
  #pragma unroll
  for(int a=0;a<2;a++)
    #pragma unroll
    for(int d=0;d<4;d++) acc[a][d]=0.f;
  const float* Xb = Xg + (size_t)b*K*256 + mg*32;
  for(int k0=0;k0<K;k0+=32){
    __syncthreads();
    #pragma unroll
    for(int p=0;p<2;p++){
      int r = p*16 + (tid>>4), c4 = (tid&15)*4;
      *(float4*)&As[r][c4] = *(const float4*)&Wt[(size_t)(k0+r)*O + o0 + c4];
    }
    {
      int r = tid>>3, c4 = (tid&7)*4;
      *(float4*)&Bs[r][c4] = *(const float4*)&Xb[(size_t)(k0+r)*256 + c4];
    }
    __syncthreads();
    #pragma unroll
    for(int k=0;k<32;k++){
      float av[2], bv[4];
      av[0]=As[k][ty*2]; av[1]=As[k][ty*2+1];
      #pragma unroll
      for(int d=0;d<4;d++) bv[d]=Bs[k][tx*4+d];
      #pragma unroll
      for(int a=0;a<2;a++)
        #pragma unroll
        for(int d=0;d<4;d++) acc[a][d]+=av[a]*bv[d];
    }
  }
  int m0 = mg*32 + tx*4;
  #pragma unroll
  for(int a=0;a<2;a++){
    int o=o0+ty*2+a;
    float* orow = Og + ((size_t)b*O + o)*256 + m0;
    float v[4];
    if(EPI==0){
      float s=p0[o]*BNS, bi=p1[o], s1=p2[o]*BNS, b1=p3[o];
      #pragma unroll
      for(int d=0;d<4;d++){ float r=fmaxf(acc[a][d]*s+bi,0.f); v[d]=2.f*r*s1+b1; }
    } else if(EPI==1){
      float bi=p0[o];
      #pragma unroll
      for(int d=0;d<4;d++) v[d]=fmaxf(acc[a][d]+bi,0.f);
    } else {
      float bi=p0[o], s2=p1[o]*BNS, b2=p2[o];
      const float* rr = res + ((size_t)b*O + o)*256 + m0;
      #pragma unroll
      for(int d=0;d<4;d++){ float u=rr[d]+acc[a][d]+bi; v[d]=u*s2+b2; }
    }
    *(float4*)orow = make_float4(v[0],v[1],v[2],v[3]);
  }
}

extern "C" void kernel_launch(void* const* d_in, const int* in_sizes, int n_in,
                              void* d_out, int out_size, void* d_ws, size_t ws_size,
                              hipStream_t stream){
  const float* xyz     =(const float*)d_in[0];
  const float* feats   =(const float*)d_in[1];
  const float* e1_w    =(const float*)d_in[2];
  const float* e1_g    =(const float*)d_in[3];
  const float* e1_b    =(const float*)d_in[4];
  const float* e2_w    =(const float*)d_in[5];
  const float* e2_g    =(const float*)d_in[6];
  const float* e2_b    =(const float*)d_in[7];
  const float* cal1_w  =(const float*)d_in[8];
  const float* cal1_g  =(const float*)d_in[9];
  const float* cal1_b  =(const float*)d_in[10];
  const float* cal2_w  =(const float*)d_in[11];
  const float* cal2_bias=(const float*)d_in[12];
  const float* exp1_w  =(const float*)d_in[13];
  const float* exp1_g  =(const float*)d_in[14];
  const float* exp1_b  =(const float*)d_in[15];
  const float* exp2_w  =(const float*)d_in[16];
  const float* exp2_g  =(const float*)d_in[17];
  const float* exp2_b  =(const float*)d_in[18];
  const float* red_w   =(const float*)d_in[19];
  const float* red_g   =(const float*)d_in[20];
  const float* red_b   =(const float*)d_in[21];
  const float* sc1_w   =(const float*)d_in[22];
  const float* sc1_b   =(const float*)d_in[23];
  const float* sc2_w   =(const float*)d_in[24];
  const float* sc2_b   =(const float*)d_in[25];
  const float* sc_n1_g =(const float*)d_in[26];
  const float* sc_n1_b =(const float*)d_in[27];
  const float* sc_n2_g =(const float*)d_in[28];
  const float* sc_n2_b =(const float*)d_in[29];

  char* wsb=(char*)d_ws;
  // layout (peak 71,303,168 B):
  // [0,2M)        idx (knn..edge2) -> then head Wt f32 (tr3..heads), 1MB
  // [2M,10M)      x0s split (knn->edge1); c1s reuses (cal1->cal2)
  // [10M,34M)     cats split [n][2][192] (edge1->exp1)
  // [34M,66M)     p1s split [n][2][256]  (exp1->exp2)
  // [69206016..)  pool f32 [b][512][256]
  // [70254592..)  x1 f32  | overlaid: Whi bf16 (dead before k_head<0>)
  // [70778880..)  hbuf f32| overlaid: Wlo bf16 tail
  int*            idx =(int*)           (wsb);
  unsigned short* x0s =(unsigned short*)(wsb + 2097152);
  unsigned short* c1s = x0s;
  unsigned short* cats=(unsigned short*)(wsb + 10485760);
  unsigned short* p1s =(unsigned short*)(wsb + 35651584);
  float*          pool=(float*)         (wsb + 69206016);
  float*          x1  =(float*)         (wsb + 70254592);
  float*          hbuf=(float*)         (wsb + 70778880);
  unsigned short* Whi =(unsigned short*)(wsb + 70254592);
  unsigned short* Wlo =(unsigned short*)(wsb + 70713344);
  float*          Wt_red=(float*)       (wsb);             // 512x256 (idx region, post-edge2)
  float*          Wt_s1 =(float*)       (wsb + 524288);    // 256x256
  float*          Wt_s2 =(float*)       (wsb + 786432);    // 256x256
  unsigned short* e1e_h=Whi;          unsigned short* e1e_l=Wlo;          // 128x64
  unsigned short* e2e_h=Whi+8192;     unsigned short* e2e_l=Wlo+8192;     // 256x64
  unsigned short* c1w_h=Whi+24576;    unsigned short* c1w_l=Wlo+24576;    // 64x192
  unsigned short* c2w_h=Whi+36864;    unsigned short* c2w_l=Wlo+36864;    // 192x64
  unsigned short* e1w_h=Whi+49152;    unsigned short* e1w_l=Wlo+49152;    // 256x192
  unsigned short* e2w_h=Whi+98304;    unsigned short* e2w_l=Wlo+98304;    // 512x256

  k_prep      <<<896,256,0,stream>>>(e1_w,e2_w,cal1_w,cal2_w,exp1_w,exp2_w,Whi,Wlo);
  k_knn       <<<512,256,0,stream>>>(xyz,feats,idx,x0s);
  k_edge2< 64><<<512,256,0,stream>>>(e1e_h,e1e_l,x0s, 128, 64,idx,e1_g,e1_b,cats, 0);
  k_edge2<128><<<512,256,0,stream>>>(e2e_h,e2e_l,cats,384,192,idx,e2_g,e2_b,cats,64);
  k_tr3       <<<256,256,0,stream>>>(red_w,sc1_w,sc2_w,Wt_red,Wt_s1,Wt_s2); // idx dead
  k_mm2<192, 64,0><<<dim3(256,1),256,0,stream>>>(c1w_h,c1w_l,cats,(void*)c1s,cal1_g,cal1_b, 64);
  k_mm2< 64, 64,1><<<dim3(256,3),256,0,stream>>>(c2w_h,c2w_l,c1s,(void*)cats,cal2_bias,cal2_bias,192);
  k_mm2<192,128,0><<<dim3(256,2),256,0,stream>>>(e1w_h,e1w_l,cats,(void*)p1s,exp1_g,exp1_b,256);
  k_mm2<256,128,2><<<dim3(256,4),256,0,stream>>>(e2w_h,e2w_l,p1s,(void*)pool,exp2_g,exp2_b,512);
  k_head<0>   <<< 64,256,0,stream>>>(Wt_red,pool,x1,  red_g,red_b,sc_n1_g,sc_n1_b,nullptr,256,512);
  k_head<1>   <<< 64,256,0,stream>>>(Wt_s1, x1,  hbuf,sc1_b,nullptr,nullptr,nullptr,nullptr,256,256);
  k_head<2>   <<< 64,256,0,stream>>>(Wt_s2, hbuf,(float*)d_out,sc2_b,sc_n2_g,sc_n2_b,nullptr,x1,256,256);
}